// Round 21
// baseline (203.366 us; speedup 1.0000x reference)
//
#include <hip/hip_runtime.h>
#include <math.h>

#define LLEN 256
#define NDIM 256
#define NHEAD 8
#define HDIM 32
#define NPIX (LLEN*LLEN)

typedef __bf16 bf16x8 __attribute__((ext_vector_type(8)));
typedef float f32x4 __attribute__((ext_vector_type(4)));

// ---- workspace layout (float offsets) ----
constexpr size_t OFF_Q     = 0;
constexpr size_t OFF_K     = 65536;
constexpr size_t OFF_V     = 131072;
constexpr size_t OFF_CAT16 = 196608;
constexpr size_t OFF_H1B   = 196608;
constexpr size_t OFF_W1B   = 360448;
constexpr size_t OFF_A1    = 1245184;
constexpr size_t OFF_ALPHA = 1769472;
constexpr size_t OFF_AGG   = 2293760;
constexpr size_t OFF_Y     = 2621440;   // also: cat16 stats partials (transient)
constexpr size_t OFF_ST16  = 2752512;
constexpr size_t OFF_ST9   = 2752544;
constexpr size_t OFF_ST136 = 2752576;
constexpr size_t OFF_PART  = 2752864;
constexpr size_t OFF_PART2 = 2892128;
constexpr size_t OFF_WZB2  = 3031392;

__device__ inline unsigned short f2b(float x){
  union { float f; unsigned u; } a; a.f = x;
  unsigned r = a.u + 0x7fffu + ((a.u >> 16) & 1u);
  return (unsigned short)(r >> 16);
}

// ============ K1: q,k,v = x @ W^T ============
__global__ __launch_bounds__(256) void qkv_kernel(
    const float* __restrict__ x, const float* __restrict__ Wq,
    const float* __restrict__ Wk, const float* __restrict__ Wv,
    float* __restrict__ q, float* __restrict__ k, float* __restrict__ v){
  __shared__ __align__(16) float xs[8][256];
  int t = threadIdx.x;
  int i0 = blockIdx.x * 8;
  int m = blockIdx.y;
  const float* W = (m==0)?Wq:((m==1)?Wk:Wv);
  float* out = (m==0)?q:((m==1)?k:v);
  for (int idx = t; idx < 2048; idx += 256)
    xs[idx>>8][idx&255] = x[(size_t)i0*256 + idx];
  __syncthreads();
  float acc[8];
  #pragma unroll
  for (int r = 0; r < 8; r++) acc[r] = 0.f;
  const float4* wr = (const float4*)(W + (size_t)t*256);
  for (int kk = 0; kk < 64; ++kk){
    float4 w4 = wr[kk];
    #pragma unroll
    for (int r = 0; r < 8; r++){
      float4 xv = ((const float4*)xs[r])[kk];
      acc[r] += w4.x*xv.x + w4.y*xv.y + w4.z*xv.z + w4.w*xv.w;
    }
  }
  #pragma unroll
  for (int r = 0; r < 8; r++) out[(size_t)(i0+r)*256 + t] = acc[r];
}

// ============ K2 v4: cat16 + fused per-block stats partials ============
__global__ __launch_bounds__(256) void cat16v4_kernel(
    const float* __restrict__ z, const float* __restrict__ qb,
    const float* __restrict__ kb, const float* __restrict__ Wp2a,
    float* __restrict__ cat16, float* __restrict__ p16, float* __restrict__ p16q){
  __shared__ __align__(16) float zs2[32*132];
  __shared__ __align__(16) float ws2[8*132];
  __shared__ float sA[512];
  int t = threadIdx.x;
  int pix0 = blockIdx.x * 32;
  int i = pix0 >> 8;
  int j0 = pix0 & 255;
  { int h = t >> 5, j = t & 31;
    float4 v = *(const float4*)(Wp2a + h*128 + j*4);
    *(float4*)(ws2 + h*132 + j*4) = v; }
  #pragma unroll
  for (int k = 0; k < 4; ++k){
    int idx = t + k*256;
    int pix = idx >> 5, j = idx & 31;
    float4 v = *(const float4*)(z + ((size_t)(pix0 + pix))*128 + j*4);
    *(float4*)(zs2 + pix*132 + j*4) = v;
  }
  __syncthreads();
  int p8 = t >> 3, h = t & 7;
  const float* zr = zs2 + p8*132;
  const float* wr = ws2 + h*132;
  float ap = 0.f;
  #pragma unroll 8
  for (int j = 0; j < 32; ++j){
    float4 a = *(const float4*)(zr + j*4);
    float4 b = *(const float4*)(wr + j*4);
    ap += a.x*b.x + a.y*b.y + a.z*b.z + a.w*b.w;
  }
  const float* qg = qb + (size_t)i*256 + h*32;
  const float* kg = kb + (size_t)(j0 + p8)*256 + h*32;
  float an = 0.f;
  #pragma unroll
  for (int d4 = 0; d4 < 8; ++d4){
    float4 a = *(const float4*)(qg + d4*4);
    float4 b = *(const float4*)(kg + d4*4);
    an += a.x*b.x + a.y*b.y + a.z*b.z + a.w*b.w;
  }
  an *= 0.17677669529663689f;
  int pix = pix0 + p8;
  cat16[(size_t)pix*16 + h] = ap;
  cat16[(size_t)pix*16 + 8 + h] = an;
  sA[p8*16 + h] = ap;
  sA[p8*16 + 8 + h] = an;
  __syncthreads();
  if (t < 16){
    float S = 0.f, Q = 0.f;
    #pragma unroll
    for (int p = 0; p < 32; ++p){ float v = sA[p*16 + t]; S += v; Q += v*v; }
    p16 [(size_t)t*2048 + blockIdx.x] = S;
    p16q[(size_t)t*2048 + blockIdx.x] = Q;
  }
}

// ============ statsA for z (kept: coalesced, BW-bound) ============
__global__ __launch_bounds__(256) void statsA_z_kernel(
    const float* __restrict__ z, float* __restrict__ part, float* __restrict__ part2){
  __shared__ float4 sm[256], sq[256];
  int t = threadIdx.x, b = blockIdx.x;
  int c4 = t & 31, po = t >> 5;
  float4 s = {0,0,0,0}, q = {0,0,0,0};
  for (int g = 0; g < 8; ++g){
    int px = b*64 + po + g*8;
    float4 v = *(const float4*)(z + (size_t)px*128 + c4*4);
    s.x += v.x; s.y += v.y; s.z += v.z; s.w += v.w;
    q.x += v.x*v.x; q.y += v.y*v.y; q.z += v.z*v.z; q.w += v.w*v.w;
  }
  sm[t] = s; sq[t] = q;
  __syncthreads();
  if (t < 32){
    float4 S = sm[t], Q = sq[t];
    for (int p2 = 1; p2 < 8; ++p2){
      float4 a = sm[p2*32 + t], c = sq[p2*32 + t];
      S.x += a.x; S.y += a.y; S.z += a.z; S.w += a.w;
      Q.x += c.x; Q.y += c.y; Q.z += c.z; Q.w += c.w;
    }
    part [(size_t)(t*4+0)*1024 + b] = S.x; part [(size_t)(t*4+1)*1024 + b] = S.y;
    part [(size_t)(t*4+2)*1024 + b] = S.z; part [(size_t)(t*4+3)*1024 + b] = S.w;
    part2[(size_t)(t*4+0)*1024 + b] = Q.x; part2[(size_t)(t*4+1)*1024 + b] = Q.y;
    part2[(size_t)(t*4+2)*1024 + b] = Q.z; part2[(size_t)(t*4+3)*1024 + b] = Q.w;
  }
}

__device__ inline void block_reduce2(float& s, float& s2, float* red){
  int t = threadIdx.x;
  int lane = t & 63, wv = t >> 6;
  #pragma unroll
  for (int o = 32; o > 0; o >>= 1){ s += __shfl_down(s, o); s2 += __shfl_down(s2, o); }
  __syncthreads();
  if (lane == 0){ red[wv] = s; red[4+wv] = s2; }
  __syncthreads();
  s  = red[0]+red[1]+red[2]+red[3];
  s2 = red[4]+red[5]+red[6]+red[7];
}

// stage B: reduce partials -> (mean, inv-std); stride-parameterized
__global__ __launch_bounds__(256) void statsB_kernel(
    const float* __restrict__ part, const float* __restrict__ part2,
    float* __restrict__ st, int C, int nb, int stride){
  __shared__ float red[8];
  int c = blockIdx.x, t = threadIdx.x;
  float s = 0.f, q = 0.f;
  for (int i = t; i < nb; i += 256){
    s += part[(size_t)c*stride + i];
    q += part2[(size_t)c*stride + i];
  }
  block_reduce2(s, q, red);
  if (t == 0){
    float m = s * (1.f/NPIX);
    float var = q * (1.f/NPIX) - m*m;
    st[c] = m;
    st[C + c] = rsqrtf(var + 1e-5f);
  }
}

// ============ small conv 3x3 v6: fused output-stats partials ============
template<int CIN, int COUT, bool PL>
__global__ __launch_bounds__(256) void conv_small6_kernel(
    const float* __restrict__ A, int Ca, const float* __restrict__ B, int Cb,
    const float* __restrict__ st, const float* __restrict__ w,
    const float* __restrict__ bias, float* __restrict__ out,
    const float* __restrict__ plddt, float* __restrict__ part,
    float* __restrict__ part2, int coff){
  constexpr int WD = 67;
  __shared__ float xn[3][CIN][WD];
  __shared__ float wsm[COUT*CIN*9];
  __shared__ float ms[CIN], isd[CIN], bs[COUT];
  __shared__ float sB[COUT*64];
  __shared__ float sP[64];
  int t = threadIdx.x;
  int i = blockIdx.x >> 2, chb = blockIdx.x & 3;
  int c0 = chb*64;
  if (t < CIN){ ms[t] = st[t]; isd[t] = st[CIN + t]; }
  if (t < COUT) bs[t] = bias[t];
  for (int idx = t; idx < COUT*CIN*9; idx += 256) wsm[idx] = w[idx];
  __syncthreads();
  constexpr int TOT = 66*CIN;
  for (int s = 0; s < 3; ++s){
    int ir = i - 1 + s;
    for (int idx = t; idx < TOT; idx += 256){
      int col = idx / CIN, c = idx - col*CIN;
      int gcol = c0 + col - 1;
      float vv = 0.f;
      if (ir >= 0 && ir < 256 && gcol >= 0 && gcol < 256){
        size_t pix = (size_t)ir*256 + gcol;
        float raw = (c < Ca) ? A[pix*Ca + c] : B[pix*Cb + (c - Ca)];
        vv = (raw - ms[c]) * isd[c];
      }
      xn[s][c][col] = vv;
    }
  }
  __syncthreads();
  int os = t >> 6, tc = t & 63;
  float a0 = bs[os*2], a1 = bs[os*2 + 1];
  #pragma unroll
  for (int kh = 0; kh < 3; ++kh){
    #pragma unroll
    for (int c = 0; c < CIN; ++c){
      float x0 = xn[kh][c][tc];
      float x1 = xn[kh][c][tc + 1];
      float x2 = xn[kh][c][tc + 2];
      const float* w0 = wsm + (((os*2+0)*CIN + c)*3 + kh)*3;
      const float* w1 = wsm + (((os*2+1)*CIN + c)*3 + kh)*3;
      a0 += x0*w0[0] + x1*w0[1] + x2*w0[2];
      a1 += x0*w1[0] + x1*w1[1] + x2*w1[2];
    }
  }
  a0 = (a0 >= 0.f) ? a0 : 0.01f*a0;
  a1 = (a1 >= 0.f) ? a1 : 0.01f*a1;
  float2 v2 = { a0, a1 };
  *(float2*)(out + ((size_t)(i*256 + c0 + tc))*COUT + os*2) = v2;
  sB[os*128 + tc]      = a0;
  sB[os*128 + 64 + tc] = a1;
  if (PL && t < 64) sP[t] = plddt[(size_t)i*256 + c0 + t];
  __syncthreads();
  if (t < COUT){
    int os2 = t >> 1, par = t & 1;
    const float* src = sB + os2*128 + par*64;
    float S = 0.f, Q = 0.f;
    #pragma unroll
    for (int j = 0; j < 64; ++j){ float v = src[j]; S += v; Q += v*v; }
    part [(size_t)(coff + t)*1024 + blockIdx.x] = S;
    part2[(size_t)(coff + t)*1024 + blockIdx.x] = Q;
  } else if (PL && t == COUT){
    float S = 0.f, Q = 0.f;
    #pragma unroll
    for (int j = 0; j < 64; ++j){ float v = sP[j]; S += v; Q += v*v; }
    part [(size_t)(coff + COUT)*1024 + blockIdx.x] = S;
    part2[(size_t)(coff + COUT)*1024 + blockIdx.x] = Q;
  }
}

// ============ aggregation (512 thr, split-j, unrolled loads) ============
__global__ __launch_bounds__(512) void agg_kernel2(
    const float* __restrict__ alpha, const float* __restrict__ z,
    const float* __restrict__ v, float* __restrict__ agg){
  __shared__ float as[2048];
  __shared__ float pp[256][4];
  __shared__ float np[256];
  int i = blockIdx.x, t = threadIdx.x;
  for (int idx = t; idx < 2048; idx += 512) as[idx] = alpha[(size_t)i*2048 + idx];
  __syncthreads();
  int tt = t & 255, jh = t >> 8;
  int p = tt & 127, hh = tt >> 7;
  const float* zrow = z + (size_t)i*32768 + (size_t)jh*128*128;
  const float* ar0 = as + jh*128*8;
  float a0=0.f, a1=0.f, a2=0.f, a3=0.f;
  #pragma unroll 8
  for (int j = 0; j < 128; ++j){
    float zv = zrow[j*128 + p];
    const float* ar = ar0 + j*8 + hh*4;
    a0 += ar[0]*zv; a1 += ar[1]*zv; a2 += ar[2]*zv; a3 += ar[3]*zv;
  }
  int h = tt >> 5;
  float an = 0.f;
  const float* vrow = v + (size_t)jh*128*256;
  const float* ah0 = as + jh*128*8;
  #pragma unroll 8
  for (int j = 0; j < 128; ++j) an += ah0[j*8 + h]*vrow[j*256 + tt];
  if (jh == 1){
    pp[tt][0]=a0; pp[tt][1]=a1; pp[tt][2]=a2; pp[tt][3]=a3; np[tt]=an;
  }
  __syncthreads();
  if (jh == 0){
    a0 += pp[tt][0]; a1 += pp[tt][1]; a2 += pp[tt][2]; a3 += pp[tt][3];
    an += np[tt];
    size_t ob = (size_t)i*1280;
    agg[ob + (hh*4+0)*128 + p] = a0;
    agg[ob + (hh*4+1)*128 + p] = a1;
    agg[ob + (hh*4+2)*128 + p] = a2;
    agg[ob + (hh*4+3)*128 + p] = a3;
    agg[ob + 1024 + tt] = an;
  }
}

// ============ out_transform: LN1 -> bf16 ============
__global__ __launch_bounds__(256) void ln1_kernel(
    const float* __restrict__ agg,
    const float* __restrict__ ln1_g, const float* __restrict__ ln1_b,
    unsigned short* __restrict__ h1b){
  __shared__ float red[8];
  int i = blockIdx.x, t = threadIdx.x;
  float v[5], s = 0.f, s2 = 0.f;
  #pragma unroll
  for (int qq = 0; qq < 5; ++qq){
    v[qq] = agg[(size_t)i*1280 + qq*256 + t];
    s += v[qq]; s2 += v[qq]*v[qq];
  }
  block_reduce2(s, s2, red);
  float m = s*(1.f/1280.f), istd = rsqrtf(s2*(1.f/1280.f) - m*m + 1e-5f);
  #pragma unroll
  for (int qq = 0; qq < 5; ++qq){
    int kk = qq*256 + t;
    h1b[(size_t)i*1280 + kk] = f2b((v[qq] - m)*istd*ln1_g[kk] + ln1_b[kk]);
  }
}

// ============ lin1_w -> bf16 ============
__global__ __launch_bounds__(256) void w1_prep(const float* __restrict__ w,
                                               unsigned short* __restrict__ wb){
  int idx = (blockIdx.x*256 + threadIdx.x)*4;
  float4 v = *(const float4*)(w + idx);
  ushort4 u;
  u.x = f2b(v.x); u.y = f2b(v.y); u.z = f2b(v.z); u.w = f2b(v.w);
  *(ushort4*)(wb + idx) = u;
}

// ============ gemm1: y[256x512] = h1b @ w1b^T + b, MFMA bf16 ============
__global__ __launch_bounds__(256) void gemm1_kernel(
    const unsigned short* __restrict__ h1b, const unsigned short* __restrict__ w1b,
    const float* __restrict__ lin1_b, float* __restrict__ y){
  int t = threadIdx.x;
  int mb = blockIdx.x & 3, nb = blockIdx.x >> 2;
  int lane = t & 63, w = t >> 6;
  int li = lane & 15, lg = lane >> 4;
  int mh = w & 1, nh = w >> 1;
  int mbase = mb*64 + mh*32, nbase = nb*64 + nh*32;
  f32x4 acc[2][2];
  #pragma unroll
  for (int a = 0; a < 2; ++a)
    #pragma unroll
    for (int b = 0; b < 2; ++b) acc[a][b] = (f32x4){0.f,0.f,0.f,0.f};
  const unsigned short* ar0 = h1b + (size_t)(mbase + li)*1280 + lg*8;
  const unsigned short* ar1 = ar0 + 16*1280;
  const unsigned short* br0 = w1b + (size_t)(nbase + li)*1280 + lg*8;
  const unsigned short* br1 = br0 + 16*1280;
  #pragma unroll 4
  for (int ks = 0; ks < 40; ++ks){
    bf16x8 a0 = *(const bf16x8*)(ar0 + ks*32);
    bf16x8 a1 = *(const bf16x8*)(ar1 + ks*32);
    bf16x8 b0 = *(const bf16x8*)(br0 + ks*32);
    bf16x8 b1 = *(const bf16x8*)(br1 + ks*32);
    acc[0][0] = __builtin_amdgcn_mfma_f32_16x16x32_bf16(a0, b0, acc[0][0], 0,0,0);
    acc[0][1] = __builtin_amdgcn_mfma_f32_16x16x32_bf16(a0, b1, acc[0][1], 0,0,0);
    acc[1][0] = __builtin_amdgcn_mfma_f32_16x16x32_bf16(a1, b0, acc[1][0], 0,0,0);
    acc[1][1] = __builtin_amdgcn_mfma_f32_16x16x32_bf16(a1, b1, acc[1][1], 0,0,0);
  }
  #pragma unroll
  for (int mi = 0; mi < 2; ++mi){
    #pragma unroll
    for (int ni = 0; ni < 2; ++ni){
      int col = nbase + ni*16 + li;
      float bb = lin1_b[col];
      #pragma unroll
      for (int ri = 0; ri < 4; ++ri){
        int row = mbase + mi*16 + lg*4 + ri;
        y[(size_t)row*512 + col] = acc[mi][ni][ri] + bb;
      }
    }
  }
}

// ============ outB v2: 2 rows/block ============
__global__ __launch_bounds__(256) void outB2_kernel(
    const float* __restrict__ y, const float* __restrict__ x,
    const float* __restrict__ ln2_g, const float* __restrict__ ln2_b,
    const float* __restrict__ lin2_w, const float* __restrict__ lin2_b,
    const float* __restrict__ lnf_g, const float* __restrict__ lnf_b,
    float* __restrict__ xout){
  __shared__ __align__(16) float h2[2][512];
  __shared__ float red[8];
  int t = threadIdx.x;
  int rb = blockIdx.x;
  for (int r = 0; r < 2; ++r){
    int i = rb*2 + r;
    float y0 = y[(size_t)i*512 + t], y1 = y[(size_t)i*512 + 256 + t];
    float s = y0 + y1, s2 = y0*y0 + y1*y1;
    block_reduce2(s, s2, red);
    float m = s*(1.f/512.f), istd = rsqrtf(s2*(1.f/512.f) - m*m + 1e-5f);
    float z0 = (y0 - m)*istd*ln2_g[t] + ln2_b[t];
    float z1 = (y1 - m)*istd*ln2_g[t+256] + ln2_b[t+256];
    h2[r][t]     = (z0 >= 0.f) ? z0 : 0.01f*z0;
    h2[r][t+256] = (z1 >= 0.f) ? z1 : 0.01f*z1;
  }
  __syncthreads();
  float acc[2];
  acc[0] = 0.f; acc[1] = 0.f;
  const float4* wr = (const float4*)(lin2_w + (size_t)t*512);
  #pragma unroll 4
  for (int kk = 0; kk < 128; ++kk){
    float4 w4 = wr[kk];
    #pragma unroll
    for (int r = 0; r < 2; ++r){
      float4 h = ((const float4*)h2[r])[kk];
      acc[r] += w4.x*h.x + w4.y*h.y + w4.z*h.z + w4.w*h.w;
    }
  }
  float bb = lin2_b[t];
  for (int r = 0; r < 2; ++r){
    int i = rb*2 + r;
    float xr = x[(size_t)i*256 + t] + acc[r] + bb;
    float s = xr, s2 = xr*xr;
    block_reduce2(s, s2, red);
    float m = s*(1.f/256.f), istd = rsqrtf(s2*(1.f/256.f) - m*m + 1e-5f);
    xout[(size_t)i*256 + t] = (xr - m)*istd*lnf_g[t] + lnf_b[t];
  }
}

// ============ conv_z weight pack ============
__global__ __launch_bounds__(256) void wz_prep2(const float* __restrict__ w,
                                                unsigned short* __restrict__ wzb2){
  int idx = blockIdx.x*256 + threadIdx.x;
  if (idx >= 23040) return;
  int lane = idx & 63;
  int f = idx >> 6;
  int k = f % 5; int ft = f / 5; int tap = ft % 9; int ocb = ft / 9;
  int oc = ocb*16 + (lane & 15);
  int chb = k*32 + (lane >> 4)*8;
  unsigned short u[8];
  #pragma unroll
  for (int j = 0; j < 8; ++j){
    int ch = chb + j;
    float vv = (ch < 136) ? w[(size_t)oc*1224 + ch*9 + tap] : 0.f;
    u[j] = f2b(vv);
  }
  uint4 pk;
  pk.x = (unsigned)u[0] | ((unsigned)u[1]<<16);
  pk.y = (unsigned)u[2] | ((unsigned)u[3]<<16);
  pk.z = (unsigned)u[4] | ((unsigned)u[5]<<16);
  pk.w = (unsigned)u[6] | ((unsigned)u[7]<<16);
  *(uint4*)(wzb2 + (size_t)idx*8) = pk;
}

// ============ conv_z v8: v7 + weight double-buffer (reg-budget safe) ========
#define LOADW8(WF, TAP) { \
  _Pragma("unroll") \
  for (int k_ = 0; k_ < 5; ++k_) \
    _Pragma("unroll") \
    for (int o_ = 0; o_ < 2; ++o_) \
      WF[k_][o_] = *(const bf16x8*)(wzb2 + (size_t)((((wocb+o_)*9 + (TAP))*5 + k_)*64 + lane)*8); }

#define CTAP8(TAP, WF) { \
  const int kh_ = (TAP)/3, kw_ = (TAP)%3; \
  _Pragma("unroll") \
  for (int r_ = 0; r_ < 2; ++r_){ \
    const unsigned short* sb_ = xs + (size_t)(r_ + kh_)*578*8; \
    _Pragma("unroll") \
    for (int k_ = 0; k_ < 5; ++k_){ \
      int cq_ = (k_ < 4) ? (k_*4 + lg) : 16; \
      bf16x8 a0_ = *(const bf16x8*)(sb_ + ((li+kw_)*17 + cq_)*8); \
      bf16x8 a1_ = *(const bf16x8*)(sb_ + ((li+kw_+16)*17 + cq_)*8); \
      acc[r_][0][0] = __builtin_amdgcn_mfma_f32_16x16x32_bf16(a0_, WF[k_][0], acc[r_][0][0], 0,0,0); \
      acc[r_][0][1] = __builtin_amdgcn_mfma_f32_16x16x32_bf16(a0_, WF[k_][1], acc[r_][0][1], 0,0,0); \
      acc[r_][1][0] = __builtin_amdgcn_mfma_f32_16x16x32_bf16(a1_, WF[k_][0], acc[r_][1][0], 0,0,0); \
      acc[r_][1][1] = __builtin_amdgcn_mfma_f32_16x16x32_bf16(a1_, WF[k_][1], acc[r_][1][1], 0,0,0); \
    } } }

__global__ __launch_bounds__(256) void conv_z8_kernel(
    const float* __restrict__ z, const float* __restrict__ alpha,
    const float* __restrict__ st, const unsigned short* __restrict__ wzb2,
    const float* __restrict__ bias, float* __restrict__ out){
  __shared__ __align__(16) unsigned short xs[4*578*8];   // 18,496 B
  __shared__ float msp[153], isp[153];
  int t = threadIdx.x;
  int stripe = blockIdx.x & 7, rg = blockIdx.x >> 3;
  int i0 = rg*2, c0 = stripe*32;
  int lane = t & 63, w = t >> 6;
  int li = lane & 15, lg = lane >> 4;
  int wocb = w*2;
  if (t < 153){
    int cq = t/9, j = t - cq*9;
    bool vld = (j < 8);
    int ch = cq*8 + j;
    msp[t] = vld ? st[ch] : 0.f;
    isp[t] = vld ? st[136 + ch] : 0.f;
  }
  __syncthreads();
  for (int it = 0; it < 3; ++it){
    int cidx = t + it*256;
    int col = cidx / 17, cq = cidx - col*17;
    int gcol = c0 + col - 1;
    float mm[8], ss[8];
    #pragma unroll
    for (int j = 0; j < 8; ++j){ mm[j] = msp[cq*9 + j]; ss[j] = isp[cq*9 + j]; }
    if (cidx < 578){
      #pragma unroll
      for (int s = 0; s < 4; ++s){
        int ir = i0 - 1 + s;
        uint4 pk = {0u,0u,0u,0u};
        if (ir >= 0 && ir < 256 && gcol >= 0 && gcol < 256){
          const float* src = (cq < 16) ? (z + ((size_t)ir*256 + gcol)*128 + cq*8)
                                       : (alpha + ((size_t)ir*256 + gcol)*8);
          float4 r0 = *(const float4*)src;
          float4 r1 = *(const float4*)(src + 4);
          unsigned short u0 = f2b((r0.x - mm[0])*ss[0]);
          unsigned short u1 = f2b((r0.y - mm[1])*ss[1]);
          unsigned short u2 = f2b((r0.z - mm[2])*ss[2]);
          unsigned short u3 = f2b((r0.w - mm[3])*ss[3]);
          unsigned short u4 = f2b((r1.x - mm[4])*ss[4]);
          unsigned short u5 = f2b((r1.y - mm[5])*ss[5]);
          unsigned short u6 = f2b((r1.z - mm[6])*ss[6]);
          unsigned short u7 = f2b((r1.w - mm[7])*ss[7]);
          pk.x = (unsigned)u0 | ((unsigned)u1<<16);
          pk.y = (unsigned)u2 | ((unsigned)u3<<16);
          pk.z = (unsigned)u4 | ((unsigned)u5<<16);
          pk.w = (unsigned)u6 | ((unsigned)u7<<16);
        }
        *(uint4*)(xs + ((size_t)(s*578 + cidx))*8) = pk;
      }
    }
  }
  __syncthreads();

  f32x4 acc[2][2][2];
  #pragma unroll
  for (int r = 0; r < 2; ++r)
    #pragma unroll
    for (int m = 0; m < 2; ++m)
      #pragma unroll
      for (int o = 0; o < 2; ++o) acc[r][m][o] = (f32x4){0.f,0.f,0.f,0.f};

  bf16x8 wfA[5][2], wfB[5][2];
  LOADW8(wfA, 0);
  LOADW8(wfB, 1); CTAP8(0, wfA);
  LOADW8(wfA, 2); CTAP8(1, wfB);
  LOADW8(wfB, 3); CTAP8(2, wfA);
  LOADW8(wfA, 4); CTAP8(3, wfB);
  LOADW8(wfB, 5); CTAP8(4, wfA);
  LOADW8(wfA, 6); CTAP8(5, wfB);
  LOADW8(wfB, 7); CTAP8(6, wfA);
  LOADW8(wfA, 8); CTAP8(7, wfB);
  CTAP8(8, wfA);

  float b0 = bias[wocb*16 + li];
  float b1 = bias[(wocb+1)*16 + li];
  #pragma unroll
  for (int r = 0; r < 2; ++r){
    int i = i0 + r;
    #pragma unroll
    for (int m = 0; m < 2; ++m){
      #pragma unroll
      for (int ri = 0; ri < 4; ++ri){
        int px = m*16 + lg*4 + ri;
        size_t obase = ((size_t)(i*256 + c0 + px))*128;
        float v0 = acc[r][m][0][ri] + b0;
        float v1 = acc[r][m][1][ri] + b1;
        v0 = (v0 >= 0.f) ? v0 : 0.01f*v0;
        v1 = (v1 >= 0.f) ? v1 : 0.01f*v1;
        out[obase + wocb*16 + li]     = v0;
        out[obase + (wocb+1)*16 + li] = v1;
      }
    }
  }
}

extern "C" void kernel_launch(void* const* d_in, const int* in_sizes, int n_in,
                              void* d_out, int out_size, void* d_ws, size_t ws_size,
                              hipStream_t stream){
  const float* x        = (const float*)d_in[0];
  const float* z        = (const float*)d_in[1];
  const float* plddt    = (const float*)d_in[2];
  const float* Wq       = (const float*)d_in[3];
  const float* Wk       = (const float*)d_in[4];
  const float* Wv       = (const float*)d_in[5];
  const float* Wp2a     = (const float*)d_in[6];
  const float* conv_a_w = (const float*)d_in[7];
  const float* conv_a_b = (const float*)d_in[8];
  const float* conv_p_w = (const float*)d_in[9];
  const float* conv_p_b = (const float*)d_in[10];
  const float* ln1_g    = (const float*)d_in[11];
  const float* ln1_b    = (const float*)d_in[12];
  const float* lin1_w   = (const float*)d_in[13];
  const float* lin1_b   = (const float*)d_in[14];
  const float* ln2_g    = (const float*)d_in[15];
  const float* ln2_b    = (const float*)d_in[16];
  const float* lin2_w   = (const float*)d_in[17];
  const float* lin2_b   = (const float*)d_in[18];
  const float* lnf_g    = (const float*)d_in[19];
  const float* lnf_b    = (const float*)d_in[20];
  const float* conv_z_w = (const float*)d_in[21];
  const float* conv_z_b = (const float*)d_in[22];

  float* ws    = (float*)d_ws;
  float* q     = ws + OFF_Q;
  float* k     = ws + OFF_K;
  float* v     = ws + OFF_V;
  float* cat16 = ws + OFF_CAT16;
  float* a1    = ws + OFF_A1;
  float* alpha = ws + OFF_ALPHA;
  float* agg   = ws + OFF_AGG;
  float* y     = ws + OFF_Y;
  float* p16   = ws + OFF_Y;           // transient: cat16 stats partials
  float* p16q  = ws + OFF_Y + 32768;   // (consumed before gemm1 writes y)
  float* st16  = ws + OFF_ST16;
  float* st9   = ws + OFF_ST9;
  float* st136 = ws + OFF_ST136;
  float* part  = ws + OFF_PART;
  float* part2 = ws + OFF_PART2;
  unsigned short* wzb2 = (unsigned short*)(ws + OFF_WZB2);
  unsigned short* h1b  = (unsigned short*)(ws + OFF_H1B);
  unsigned short* w1b  = (unsigned short*)(ws + OFF_W1B);

  float* xout = (float*)d_out;
  float* zout = (float*)d_out + 65536;

  qkv_kernel<<<dim3(32,3), 256, 0, stream>>>(x, Wq, Wk, Wv, q, k, v);
  cat16v4_kernel<<<2048, 256, 0, stream>>>(z, q, k, Wp2a, cat16, p16, p16q);
  statsB_kernel<<<16, 256, 0, stream>>>(p16, p16q, st16, 16, 2048, 2048);
  conv_small6_kernel<16,8,true><<<1024, 256, 0, stream>>>(
      cat16, 16, (const float*)nullptr, 0, st16, conv_a_w, conv_a_b, a1,
      plddt, part, part2, 0);
  statsB_kernel<<<9, 256, 0, stream>>>(part, part2, st9, 9, 1024, 1024);
  conv_small6_kernel<9,8,false><<<1024, 256, 0, stream>>>(
      a1, 8, plddt, 1, st9, conv_p_w, conv_p_b, alpha,
      (const float*)nullptr, part, part2, 128);
  agg_kernel2<<<256, 512, 0, stream>>>(alpha, z, v, agg);
  w1_prep<<<640, 256, 0, stream>>>(lin1_w, w1b);
  ln1_kernel<<<256, 256, 0, stream>>>(agg, ln1_g, ln1_b, h1b);
  gemm1_kernel<<<32, 256, 0, stream>>>(h1b, w1b, lin1_b, y);
  outB2_kernel<<<128, 256, 0, stream>>>(y, x, ln2_g, ln2_b, lin2_w, lin2_b,
                                        lnf_g, lnf_b, xout);
  statsA_z_kernel<<<1024, 256, 0, stream>>>(z, part, part2);
  statsB_kernel<<<136, 256, 0, stream>>>(part, part2, st136, 136, 1024, 1024);
  wz_prep2<<<90, 256, 0, stream>>>(conv_z_w, wzb2);
  conv_z8_kernel<<<1024, 256, 0, stream>>>(z, alpha, st136, wzb2, conv_z_b, zout);
}

// Round 22
// 181.982 us; speedup vs baseline: 1.1175x; 1.1175x over previous
//
#include <hip/hip_runtime.h>
#include <math.h>

#define LLEN 256
#define NDIM 256
#define NHEAD 8
#define HDIM 32
#define NPIX (LLEN*LLEN)

typedef __bf16 bf16x8 __attribute__((ext_vector_type(8)));
typedef float f32x4 __attribute__((ext_vector_type(4)));

// ---- workspace layout (float offsets) ----
constexpr size_t OFF_Q     = 0;
constexpr size_t OFF_K     = 65536;
constexpr size_t OFF_V     = 131072;
constexpr size_t OFF_CAT16 = 196608;
constexpr size_t OFF_H1B   = 196608;
constexpr size_t OFF_W1B   = 360448;
constexpr size_t OFF_A1    = 1245184;
constexpr size_t OFF_ALPHA = 1769472;
constexpr size_t OFF_AGG   = 2293760;
constexpr size_t OFF_Y     = 2621440;   // also: cat16 stats partials (transient)
constexpr size_t OFF_ST16  = 2752512;
constexpr size_t OFF_ST9   = 2752544;
constexpr size_t OFF_ST136 = 2752576;
constexpr size_t OFF_PART  = 2752864;
constexpr size_t OFF_PART2 = 2892128;
constexpr size_t OFF_WZB2  = 3031392;

__device__ inline unsigned short f2b(float x){
  union { float f; unsigned u; } a; a.f = x;
  unsigned r = a.u + 0x7fffu + ((a.u >> 16) & 1u);
  return (unsigned short)(r >> 16);
}

// ============ K1 v2: q,k,v = x @ W^T (4 rows/block, 192 blocks) ============
__global__ __launch_bounds__(256) void qkv2_kernel(
    const float* __restrict__ x, const float* __restrict__ Wq,
    const float* __restrict__ Wk, const float* __restrict__ Wv,
    float* __restrict__ q, float* __restrict__ k, float* __restrict__ v){
  __shared__ __align__(16) float xs[4][256];
  int t = threadIdx.x;
  int i0 = blockIdx.x * 4;
  int m = blockIdx.y;
  const float* W = (m==0)?Wq:((m==1)?Wk:Wv);
  float* out = (m==0)?q:((m==1)?k:v);
  for (int idx = t; idx < 1024; idx += 256)
    xs[idx>>8][idx&255] = x[(size_t)i0*256 + idx];
  __syncthreads();
  float acc[4];
  #pragma unroll
  for (int r = 0; r < 4; r++) acc[r] = 0.f;
  const float4* wr = (const float4*)(W + (size_t)t*256);
  for (int kk = 0; kk < 64; ++kk){
    float4 w4 = wr[kk];
    #pragma unroll
    for (int r = 0; r < 4; r++){
      float4 xv = ((const float4*)xs[r])[kk];
      acc[r] += w4.x*xv.x + w4.y*xv.y + w4.z*xv.z + w4.w*xv.w;
    }
  }
  #pragma unroll
  for (int r = 0; r < 4; r++) out[(size_t)(i0+r)*256 + t] = acc[r];
}

// ============ K2 v4: cat16 + fused per-block stats partials ============
__global__ __launch_bounds__(256) void cat16v4_kernel(
    const float* __restrict__ z, const float* __restrict__ qb,
    const float* __restrict__ kb, const float* __restrict__ Wp2a,
    float* __restrict__ cat16, float* __restrict__ p16, float* __restrict__ p16q){
  __shared__ __align__(16) float zs2[32*132];
  __shared__ __align__(16) float ws2[8*132];
  __shared__ float sA[512];
  int t = threadIdx.x;
  int pix0 = blockIdx.x * 32;
  int i = pix0 >> 8;
  int j0 = pix0 & 255;
  { int h = t >> 5, j = t & 31;
    float4 v = *(const float4*)(Wp2a + h*128 + j*4);
    *(float4*)(ws2 + h*132 + j*4) = v; }
  #pragma unroll
  for (int k = 0; k < 4; ++k){
    int idx = t + k*256;
    int pix = idx >> 5, j = idx & 31;
    float4 v = *(const float4*)(z + ((size_t)(pix0 + pix))*128 + j*4);
    *(float4*)(zs2 + pix*132 + j*4) = v;
  }
  __syncthreads();
  int p8 = t >> 3, h = t & 7;
  const float* zr = zs2 + p8*132;
  const float* wr = ws2 + h*132;
  float ap = 0.f;
  #pragma unroll 8
  for (int j = 0; j < 32; ++j){
    float4 a = *(const float4*)(zr + j*4);
    float4 b = *(const float4*)(wr + j*4);
    ap += a.x*b.x + a.y*b.y + a.z*b.z + a.w*b.w;
  }
  const float* qg = qb + (size_t)i*256 + h*32;
  const float* kg = kb + (size_t)(j0 + p8)*256 + h*32;
  float an = 0.f;
  #pragma unroll
  for (int d4 = 0; d4 < 8; ++d4){
    float4 a = *(const float4*)(qg + d4*4);
    float4 b = *(const float4*)(kg + d4*4);
    an += a.x*b.x + a.y*b.y + a.z*b.z + a.w*b.w;
  }
  an *= 0.17677669529663689f;
  int pix = pix0 + p8;
  cat16[(size_t)pix*16 + h] = ap;
  cat16[(size_t)pix*16 + 8 + h] = an;
  sA[p8*16 + h] = ap;
  sA[p8*16 + 8 + h] = an;
  __syncthreads();
  if (t < 16){
    float S = 0.f, Q = 0.f;
    #pragma unroll
    for (int p = 0; p < 32; ++p){ float v = sA[p*16 + t]; S += v; Q += v*v; }
    p16 [(size_t)t*2048 + blockIdx.x] = S;
    p16q[(size_t)t*2048 + blockIdx.x] = Q;
  }
}

// ============ statsA for z (kept: coalesced, BW-bound) ============
__global__ __launch_bounds__(256) void statsA_z_kernel(
    const float* __restrict__ z, float* __restrict__ part, float* __restrict__ part2){
  __shared__ float4 sm[256], sq[256];
  int t = threadIdx.x, b = blockIdx.x;
  int c4 = t & 31, po = t >> 5;
  float4 s = {0,0,0,0}, q = {0,0,0,0};
  for (int g = 0; g < 8; ++g){
    int px = b*64 + po + g*8;
    float4 v = *(const float4*)(z + (size_t)px*128 + c4*4);
    s.x += v.x; s.y += v.y; s.z += v.z; s.w += v.w;
    q.x += v.x*v.x; q.y += v.y*v.y; q.z += v.z*v.z; q.w += v.w*v.w;
  }
  sm[t] = s; sq[t] = q;
  __syncthreads();
  if (t < 32){
    float4 S = sm[t], Q = sq[t];
    for (int p2 = 1; p2 < 8; ++p2){
      float4 a = sm[p2*32 + t], c = sq[p2*32 + t];
      S.x += a.x; S.y += a.y; S.z += a.z; S.w += a.w;
      Q.x += c.x; Q.y += c.y; Q.z += c.z; Q.w += c.w;
    }
    part [(size_t)(t*4+0)*1024 + b] = S.x; part [(size_t)(t*4+1)*1024 + b] = S.y;
    part [(size_t)(t*4+2)*1024 + b] = S.z; part [(size_t)(t*4+3)*1024 + b] = S.w;
    part2[(size_t)(t*4+0)*1024 + b] = Q.x; part2[(size_t)(t*4+1)*1024 + b] = Q.y;
    part2[(size_t)(t*4+2)*1024 + b] = Q.z; part2[(size_t)(t*4+3)*1024 + b] = Q.w;
  }
}

__device__ inline void block_reduce2(float& s, float& s2, float* red){
  int t = threadIdx.x;
  int lane = t & 63, wv = t >> 6;
  #pragma unroll
  for (int o = 32; o > 0; o >>= 1){ s += __shfl_down(s, o); s2 += __shfl_down(s2, o); }
  __syncthreads();
  if (lane == 0){ red[wv] = s; red[4+wv] = s2; }
  __syncthreads();
  s  = red[0]+red[1]+red[2]+red[3];
  s2 = red[4]+red[5]+red[6]+red[7];
}

// stage B: reduce partials -> (mean, inv-std); stride-parameterized
__global__ __launch_bounds__(256) void statsB_kernel(
    const float* __restrict__ part, const float* __restrict__ part2,
    float* __restrict__ st, int C, int nb, int stride){
  __shared__ float red[8];
  int c = blockIdx.x, t = threadIdx.x;
  float s = 0.f, q = 0.f;
  for (int i = t; i < nb; i += 256){
    s += part[(size_t)c*stride + i];
    q += part2[(size_t)c*stride + i];
  }
  block_reduce2(s, q, red);
  if (t == 0){
    float m = s * (1.f/NPIX);
    float var = q * (1.f/NPIX) - m*m;
    st[c] = m;
    st[C + c] = rsqrtf(var + 1e-5f);
  }
}

// ============ small conv 3x3 v6: fused output-stats partials ============
template<int CIN, int COUT, bool PL>
__global__ __launch_bounds__(256) void conv_small6_kernel(
    const float* __restrict__ A, int Ca, const float* __restrict__ B, int Cb,
    const float* __restrict__ st, const float* __restrict__ w,
    const float* __restrict__ bias, float* __restrict__ out,
    const float* __restrict__ plddt, float* __restrict__ part,
    float* __restrict__ part2, int coff){
  constexpr int WD = 67;
  __shared__ float xn[3][CIN][WD];
  __shared__ float wsm[COUT*CIN*9];
  __shared__ float ms[CIN], isd[CIN], bs[COUT];
  __shared__ float sB[COUT*64];
  __shared__ float sP[64];
  int t = threadIdx.x;
  int i = blockIdx.x >> 2, chb = blockIdx.x & 3;
  int c0 = chb*64;
  if (t < CIN){ ms[t] = st[t]; isd[t] = st[CIN + t]; }
  if (t < COUT) bs[t] = bias[t];
  for (int idx = t; idx < COUT*CIN*9; idx += 256) wsm[idx] = w[idx];
  __syncthreads();
  constexpr int TOT = 66*CIN;
  for (int s = 0; s < 3; ++s){
    int ir = i - 1 + s;
    for (int idx = t; idx < TOT; idx += 256){
      int col = idx / CIN, c = idx - col*CIN;
      int gcol = c0 + col - 1;
      float vv = 0.f;
      if (ir >= 0 && ir < 256 && gcol >= 0 && gcol < 256){
        size_t pix = (size_t)ir*256 + gcol;
        float raw = (c < Ca) ? A[pix*Ca + c] : B[pix*Cb + (c - Ca)];
        vv = (raw - ms[c]) * isd[c];
      }
      xn[s][c][col] = vv;
    }
  }
  __syncthreads();
  int os = t >> 6, tc = t & 63;
  float a0 = bs[os*2], a1 = bs[os*2 + 1];
  #pragma unroll
  for (int kh = 0; kh < 3; ++kh){
    #pragma unroll
    for (int c = 0; c < CIN; ++c){
      float x0 = xn[kh][c][tc];
      float x1 = xn[kh][c][tc + 1];
      float x2 = xn[kh][c][tc + 2];
      const float* w0 = wsm + (((os*2+0)*CIN + c)*3 + kh)*3;
      const float* w1 = wsm + (((os*2+1)*CIN + c)*3 + kh)*3;
      a0 += x0*w0[0] + x1*w0[1] + x2*w0[2];
      a1 += x0*w1[0] + x1*w1[1] + x2*w1[2];
    }
  }
  a0 = (a0 >= 0.f) ? a0 : 0.01f*a0;
  a1 = (a1 >= 0.f) ? a1 : 0.01f*a1;
  float2 v2 = { a0, a1 };
  *(float2*)(out + ((size_t)(i*256 + c0 + tc))*COUT + os*2) = v2;
  sB[os*128 + tc]      = a0;
  sB[os*128 + 64 + tc] = a1;
  if (PL && t < 64) sP[t] = plddt[(size_t)i*256 + c0 + t];
  __syncthreads();
  if (t < COUT){
    int os2 = t >> 1, par = t & 1;
    const float* src = sB + os2*128 + par*64;
    float S = 0.f, Q = 0.f;
    #pragma unroll
    for (int j = 0; j < 64; ++j){ float v = src[j]; S += v; Q += v*v; }
    part [(size_t)(coff + t)*1024 + blockIdx.x] = S;
    part2[(size_t)(coff + t)*1024 + blockIdx.x] = Q;
  } else if (PL && t == COUT){
    float S = 0.f, Q = 0.f;
    #pragma unroll
    for (int j = 0; j < 64; ++j){ float v = sP[j]; S += v; Q += v*v; }
    part [(size_t)(coff + COUT)*1024 + blockIdx.x] = S;
    part2[(size_t)(coff + COUT)*1024 + blockIdx.x] = Q;
  }
}

// ============ aggregation (512 thr, split-j, unrolled loads) ============
__global__ __launch_bounds__(512) void agg_kernel2(
    const float* __restrict__ alpha, const float* __restrict__ z,
    const float* __restrict__ v, float* __restrict__ agg){
  __shared__ float as[2048];
  __shared__ float pp[256][4];
  __shared__ float np[256];
  int i = blockIdx.x, t = threadIdx.x;
  for (int idx = t; idx < 2048; idx += 512) as[idx] = alpha[(size_t)i*2048 + idx];
  __syncthreads();
  int tt = t & 255, jh = t >> 8;
  int p = tt & 127, hh = tt >> 7;
  const float* zrow = z + (size_t)i*32768 + (size_t)jh*128*128;
  const float* ar0 = as + jh*128*8;
  float a0=0.f, a1=0.f, a2=0.f, a3=0.f;
  #pragma unroll 8
  for (int j = 0; j < 128; ++j){
    float zv = zrow[j*128 + p];
    const float* ar = ar0 + j*8 + hh*4;
    a0 += ar[0]*zv; a1 += ar[1]*zv; a2 += ar[2]*zv; a3 += ar[3]*zv;
  }
  int h = tt >> 5;
  float an = 0.f;
  const float* vrow = v + (size_t)jh*128*256;
  const float* ah0 = as + jh*128*8;
  #pragma unroll 8
  for (int j = 0; j < 128; ++j) an += ah0[j*8 + h]*vrow[j*256 + tt];
  if (jh == 1){
    pp[tt][0]=a0; pp[tt][1]=a1; pp[tt][2]=a2; pp[tt][3]=a3; np[tt]=an;
  }
  __syncthreads();
  if (jh == 0){
    a0 += pp[tt][0]; a1 += pp[tt][1]; a2 += pp[tt][2]; a3 += pp[tt][3];
    an += np[tt];
    size_t ob = (size_t)i*1280;
    agg[ob + (hh*4+0)*128 + p] = a0;
    agg[ob + (hh*4+1)*128 + p] = a1;
    agg[ob + (hh*4+2)*128 + p] = a2;
    agg[ob + (hh*4+3)*128 + p] = a3;
    agg[ob + 1024 + tt] = an;
  }
}

// ============ out_transform: LN1 -> bf16 ============
__global__ __launch_bounds__(256) void ln1_kernel(
    const float* __restrict__ agg,
    const float* __restrict__ ln1_g, const float* __restrict__ ln1_b,
    unsigned short* __restrict__ h1b){
  __shared__ float red[8];
  int i = blockIdx.x, t = threadIdx.x;
  float v[5], s = 0.f, s2 = 0.f;
  #pragma unroll
  for (int qq = 0; qq < 5; ++qq){
    v[qq] = agg[(size_t)i*1280 + qq*256 + t];
    s += v[qq]; s2 += v[qq]*v[qq];
  }
  block_reduce2(s, s2, red);
  float m = s*(1.f/1280.f), istd = rsqrtf(s2*(1.f/1280.f) - m*m + 1e-5f);
  #pragma unroll
  for (int qq = 0; qq < 5; ++qq){
    int kk = qq*256 + t;
    h1b[(size_t)i*1280 + kk] = f2b((v[qq] - m)*istd*ln1_g[kk] + ln1_b[kk]);
  }
}

// ============ lin1_w -> bf16 ============
__global__ __launch_bounds__(256) void w1_prep(const float* __restrict__ w,
                                               unsigned short* __restrict__ wb){
  int idx = (blockIdx.x*256 + threadIdx.x)*4;
  float4 v = *(const float4*)(w + idx);
  ushort4 u;
  u.x = f2b(v.x); u.y = f2b(v.y); u.z = f2b(v.z); u.w = f2b(v.w);
  *(ushort4*)(wb + idx) = u;
}

// ============ gemm1: y[256x512] = h1b @ w1b^T + b, MFMA bf16 ============
__global__ __launch_bounds__(256) void gemm1_kernel(
    const unsigned short* __restrict__ h1b, const unsigned short* __restrict__ w1b,
    const float* __restrict__ lin1_b, float* __restrict__ y){
  int t = threadIdx.x;
  int mb = blockIdx.x & 3, nb = blockIdx.x >> 2;
  int lane = t & 63, w = t >> 6;
  int li = lane & 15, lg = lane >> 4;
  int mh = w & 1, nh = w >> 1;
  int mbase = mb*64 + mh*32, nbase = nb*64 + nh*32;
  f32x4 acc[2][2];
  #pragma unroll
  for (int a = 0; a < 2; ++a)
    #pragma unroll
    for (int b = 0; b < 2; ++b) acc[a][b] = (f32x4){0.f,0.f,0.f,0.f};
  const unsigned short* ar0 = h1b + (size_t)(mbase + li)*1280 + lg*8;
  const unsigned short* ar1 = ar0 + 16*1280;
  const unsigned short* br0 = w1b + (size_t)(nbase + li)*1280 + lg*8;
  const unsigned short* br1 = br0 + 16*1280;
  #pragma unroll 4
  for (int ks = 0; ks < 40; ++ks){
    bf16x8 a0 = *(const bf16x8*)(ar0 + ks*32);
    bf16x8 a1 = *(const bf16x8*)(ar1 + ks*32);
    bf16x8 b0 = *(const bf16x8*)(br0 + ks*32);
    bf16x8 b1 = *(const bf16x8*)(br1 + ks*32);
    acc[0][0] = __builtin_amdgcn_mfma_f32_16x16x32_bf16(a0, b0, acc[0][0], 0,0,0);
    acc[0][1] = __builtin_amdgcn_mfma_f32_16x16x32_bf16(a0, b1, acc[0][1], 0,0,0);
    acc[1][0] = __builtin_amdgcn_mfma_f32_16x16x32_bf16(a1, b0, acc[1][0], 0,0,0);
    acc[1][1] = __builtin_amdgcn_mfma_f32_16x16x32_bf16(a1, b1, acc[1][1], 0,0,0);
  }
  #pragma unroll
  for (int mi = 0; mi < 2; ++mi){
    #pragma unroll
    for (int ni = 0; ni < 2; ++ni){
      int col = nbase + ni*16 + li;
      float bb = lin1_b[col];
      #pragma unroll
      for (int ri = 0; ri < 4; ++ri){
        int row = mbase + mi*16 + lg*4 + ri;
        y[(size_t)row*512 + col] = acc[mi][ni][ri] + bb;
      }
    }
  }
}

// ============ outB v2: 2 rows/block ============
__global__ __launch_bounds__(256) void outB2_kernel(
    const float* __restrict__ y, const float* __restrict__ x,
    const float* __restrict__ ln2_g, const float* __restrict__ ln2_b,
    const float* __restrict__ lin2_w, const float* __restrict__ lin2_b,
    const float* __restrict__ lnf_g, const float* __restrict__ lnf_b,
    float* __restrict__ xout){
  __shared__ __align__(16) float h2[2][512];
  __shared__ float red[8];
  int t = threadIdx.x;
  int rb = blockIdx.x;
  for (int r = 0; r < 2; ++r){
    int i = rb*2 + r;
    float y0 = y[(size_t)i*512 + t], y1 = y[(size_t)i*512 + 256 + t];
    float s = y0 + y1, s2 = y0*y0 + y1*y1;
    block_reduce2(s, s2, red);
    float m = s*(1.f/512.f), istd = rsqrtf(s2*(1.f/512.f) - m*m + 1e-5f);
    float z0 = (y0 - m)*istd*ln2_g[t] + ln2_b[t];
    float z1 = (y1 - m)*istd*ln2_g[t+256] + ln2_b[t+256];
    h2[r][t]     = (z0 >= 0.f) ? z0 : 0.01f*z0;
    h2[r][t+256] = (z1 >= 0.f) ? z1 : 0.01f*z1;
  }
  __syncthreads();
  float acc[2];
  acc[0] = 0.f; acc[1] = 0.f;
  const float4* wr = (const float4*)(lin2_w + (size_t)t*512);
  #pragma unroll 4
  for (int kk = 0; kk < 128; ++kk){
    float4 w4 = wr[kk];
    #pragma unroll
    for (int r = 0; r < 2; ++r){
      float4 h = ((const float4*)h2[r])[kk];
      acc[r] += w4.x*h.x + w4.y*h.y + w4.z*h.z + w4.w*h.w;
    }
  }
  float bb = lin2_b[t];
  for (int r = 0; r < 2; ++r){
    int i = rb*2 + r;
    float xr = x[(size_t)i*256 + t] + acc[r] + bb;
    float s = xr, s2 = xr*xr;
    block_reduce2(s, s2, red);
    float m = s*(1.f/256.f), istd = rsqrtf(s2*(1.f/256.f) - m*m + 1e-5f);
    xout[(size_t)i*256 + t] = (xr - m)*istd*lnf_g[t] + lnf_b[t];
  }
}

// ============ conv_z weight pack ============
__global__ __launch_bounds__(256) void wz_prep2(const float* __restrict__ w,
                                                unsigned short* __restrict__ wzb2){
  int idx = blockIdx.x*256 + threadIdx.x;
  if (idx >= 23040) return;
  int lane = idx & 63;
  int f = idx >> 6;
  int k = f % 5; int ft = f / 5; int tap = ft % 9; int ocb = ft / 9;
  int oc = ocb*16 + (lane & 15);
  int chb = k*32 + (lane >> 4)*8;
  unsigned short u[8];
  #pragma unroll
  for (int j = 0; j < 8; ++j){
    int ch = chb + j;
    float vv = (ch < 136) ? w[(size_t)oc*1224 + ch*9 + tap] : 0.f;
    u[j] = f2b(vv);
  }
  uint4 pk;
  pk.x = (unsigned)u[0] | ((unsigned)u[1]<<16);
  pk.y = (unsigned)u[2] | ((unsigned)u[3]<<16);
  pk.z = (unsigned)u[4] | ((unsigned)u[5]<<16);
  pk.w = (unsigned)u[6] | ((unsigned)u[7]<<16);
  *(uint4*)(wzb2 + (size_t)idx*8) = pk;
}

// ============ conv_z v7: 2-row groups, small LDS (settled local optimum) =====
__global__ __launch_bounds__(256) void conv_z7_kernel(
    const float* __restrict__ z, const float* __restrict__ alpha,
    const float* __restrict__ st, const unsigned short* __restrict__ wzb2,
    const float* __restrict__ bias, float* __restrict__ out){
  __shared__ __align__(16) unsigned short xs[4*578*8];   // 18,496 B
  __shared__ float msp[153], isp[153];
  int t = threadIdx.x;
  int stripe = blockIdx.x & 7, rg = blockIdx.x >> 3;
  int i0 = rg*2, c0 = stripe*32;
  int lane = t & 63, w = t >> 6;
  int li = lane & 15, lg = lane >> 4;
  int wocb = w*2;
  if (t < 153){
    int cq = t/9, j = t - cq*9;
    bool vld = (j < 8);
    int ch = cq*8 + j;
    msp[t] = vld ? st[ch] : 0.f;
    isp[t] = vld ? st[136 + ch] : 0.f;
  }
  __syncthreads();
  for (int it = 0; it < 3; ++it){
    int cidx = t + it*256;
    int col = cidx / 17, cq = cidx - col*17;
    int gcol = c0 + col - 1;
    float mm[8], ss[8];
    #pragma unroll
    for (int j = 0; j < 8; ++j){ mm[j] = msp[cq*9 + j]; ss[j] = isp[cq*9 + j]; }
    if (cidx < 578){
      #pragma unroll
      for (int s = 0; s < 4; ++s){
        int ir = i0 - 1 + s;
        uint4 pk = {0u,0u,0u,0u};
        if (ir >= 0 && ir < 256 && gcol >= 0 && gcol < 256){
          const float* src = (cq < 16) ? (z + ((size_t)ir*256 + gcol)*128 + cq*8)
                                       : (alpha + ((size_t)ir*256 + gcol)*8);
          float4 r0 = *(const float4*)src;
          float4 r1 = *(const float4*)(src + 4);
          unsigned short u0 = f2b((r0.x - mm[0])*ss[0]);
          unsigned short u1 = f2b((r0.y - mm[1])*ss[1]);
          unsigned short u2 = f2b((r0.z - mm[2])*ss[2]);
          unsigned short u3 = f2b((r0.w - mm[3])*ss[3]);
          unsigned short u4 = f2b((r1.x - mm[4])*ss[4]);
          unsigned short u5 = f2b((r1.y - mm[5])*ss[5]);
          unsigned short u6 = f2b((r1.z - mm[6])*ss[6]);
          unsigned short u7 = f2b((r1.w - mm[7])*ss[7]);
          pk.x = (unsigned)u0 | ((unsigned)u1<<16);
          pk.y = (unsigned)u2 | ((unsigned)u3<<16);
          pk.z = (unsigned)u4 | ((unsigned)u5<<16);
          pk.w = (unsigned)u6 | ((unsigned)u7<<16);
        }
        *(uint4*)(xs + ((size_t)(s*578 + cidx))*8) = pk;
      }
    }
  }
  __syncthreads();

  f32x4 acc[2][2][2];
  #pragma unroll
  for (int r = 0; r < 2; ++r)
    #pragma unroll
    for (int m = 0; m < 2; ++m)
      #pragma unroll
      for (int o = 0; o < 2; ++o) acc[r][m][o] = (f32x4){0.f,0.f,0.f,0.f};

  for (int kh = 0; kh < 3; ++kh){
    for (int kw = 0; kw < 3; ++kw){
      int tap = kh*3 + kw;
      bf16x8 wf[5][2];
      #pragma unroll
      for (int k = 0; k < 5; ++k)
        #pragma unroll
        for (int o = 0; o < 2; ++o)
          wf[k][o] = *(const bf16x8*)(wzb2 + (size_t)((((wocb+o)*9 + tap)*5 + k)*64 + lane)*8);
      #pragma unroll
      for (int r = 0; r < 2; ++r){
        const unsigned short* sb = xs + (size_t)(r + kh)*578*8;
        #pragma unroll
        for (int k = 0; k < 5; ++k){
          int cq = (k < 4) ? (k*4 + lg) : 16;
          bf16x8 a0 = *(const bf16x8*)(sb + ((li+kw)*17 + cq)*8);
          bf16x8 a1 = *(const bf16x8*)(sb + ((li+kw+16)*17 + cq)*8);
          acc[r][0][0] = __builtin_amdgcn_mfma_f32_16x16x32_bf16(a0, wf[k][0], acc[r][0][0], 0,0,0);
          acc[r][0][1] = __builtin_amdgcn_mfma_f32_16x16x32_bf16(a0, wf[k][1], acc[r][0][1], 0,0,0);
          acc[r][1][0] = __builtin_amdgcn_mfma_f32_16x16x32_bf16(a1, wf[k][0], acc[r][1][0], 0,0,0);
          acc[r][1][1] = __builtin_amdgcn_mfma_f32_16x16x32_bf16(a1, wf[k][1], acc[r][1][1], 0,0,0);
        }
      }
    }
  }

  float b0 = bias[wocb*16 + li];
  float b1 = bias[(wocb+1)*16 + li];
  #pragma unroll
  for (int r = 0; r < 2; ++r){
    int i = i0 + r;
    #pragma unroll
    for (int m = 0; m < 2; ++m){
      #pragma unroll
      for (int ri = 0; ri < 4; ++ri){
        int px = m*16 + lg*4 + ri;
        size_t obase = ((size_t)(i*256 + c0 + px))*128;
        float v0 = acc[r][m][0][ri] + b0;
        float v1 = acc[r][m][1][ri] + b1;
        v0 = (v0 >= 0.f) ? v0 : 0.01f*v0;
        v1 = (v1 >= 0.f) ? v1 : 0.01f*v1;
        out[obase + wocb*16 + li]     = v0;
        out[obase + (wocb+1)*16 + li] = v1;
      }
    }
  }
}

extern "C" void kernel_launch(void* const* d_in, const int* in_sizes, int n_in,
                              void* d_out, int out_size, void* d_ws, size_t ws_size,
                              hipStream_t stream){
  const float* x        = (const float*)d_in[0];
  const float* z        = (const float*)d_in[1];
  const float* plddt    = (const float*)d_in[2];
  const float* Wq       = (const float*)d_in[3];
  const float* Wk       = (const float*)d_in[4];
  const float* Wv       = (const float*)d_in[5];
  const float* Wp2a     = (const float*)d_in[6];
  const float* conv_a_w = (const float*)d_in[7];
  const float* conv_a_b = (const float*)d_in[8];
  const float* conv_p_w = (const float*)d_in[9];
  const float* conv_p_b = (const float*)d_in[10];
  const float* ln1_g    = (const float*)d_in[11];
  const float* ln1_b    = (const float*)d_in[12];
  const float* lin1_w   = (const float*)d_in[13];
  const float* lin1_b   = (const float*)d_in[14];
  const float* ln2_g    = (const float*)d_in[15];
  const float* ln2_b    = (const float*)d_in[16];
  const float* lin2_w   = (const float*)d_in[17];
  const float* lin2_b   = (const float*)d_in[18];
  const float* lnf_g    = (const float*)d_in[19];
  const float* lnf_b    = (const float*)d_in[20];
  const float* conv_z_w = (const float*)d_in[21];
  const float* conv_z_b = (const float*)d_in[22];

  float* ws    = (float*)d_ws;
  float* q     = ws + OFF_Q;
  float* k     = ws + OFF_K;
  float* v     = ws + OFF_V;
  float* cat16 = ws + OFF_CAT16;
  float* a1    = ws + OFF_A1;
  float* alpha = ws + OFF_ALPHA;
  float* agg   = ws + OFF_AGG;
  float* y     = ws + OFF_Y;
  float* p16   = ws + OFF_Y;           // transient: cat16 stats partials
  float* p16q  = ws + OFF_Y + 32768;   // (consumed before gemm1 writes y)
  float* st16  = ws + OFF_ST16;
  float* st9   = ws + OFF_ST9;
  float* st136 = ws + OFF_ST136;
  float* part  = ws + OFF_PART;
  float* part2 = ws + OFF_PART2;
  unsigned short* wzb2 = (unsigned short*)(ws + OFF_WZB2);
  unsigned short* h1b  = (unsigned short*)(ws + OFF_H1B);
  unsigned short* w1b  = (unsigned short*)(ws + OFF_W1B);

  float* xout = (float*)d_out;
  float* zout = (float*)d_out + 65536;

  qkv2_kernel<<<dim3(64,3), 256, 0, stream>>>(x, Wq, Wk, Wv, q, k, v);
  cat16v4_kernel<<<2048, 256, 0, stream>>>(z, q, k, Wp2a, cat16, p16, p16q);
  statsB_kernel<<<16, 256, 0, stream>>>(p16, p16q, st16, 16, 2048, 2048);
  conv_small6_kernel<16,8,true><<<1024, 256, 0, stream>>>(
      cat16, 16, (const float*)nullptr, 0, st16, conv_a_w, conv_a_b, a1,
      plddt, part, part2, 0);
  statsB_kernel<<<9, 256, 0, stream>>>(part, part2, st9, 9, 1024, 1024);
  conv_small6_kernel<9,8,false><<<1024, 256, 0, stream>>>(
      a1, 8, plddt, 1, st9, conv_p_w, conv_p_b, alpha,
      (const float*)nullptr, part, part2, 128);
  agg_kernel2<<<256, 512, 0, stream>>>(alpha, z, v, agg);
  w1_prep<<<640, 256, 0, stream>>>(lin1_w, w1b);
  ln1_kernel<<<256, 256, 0, stream>>>(agg, ln1_g, ln1_b, h1b);
  gemm1_kernel<<<32, 256, 0, stream>>>(h1b, w1b, lin1_b, y);
  outB2_kernel<<<128, 256, 0, stream>>>(y, x, ln2_g, ln2_b, lin2_w, lin2_b,
                                        lnf_g, lnf_b, xout);
  statsA_z_kernel<<<1024, 256, 0, stream>>>(z, part, part2);
  statsB_kernel<<<136, 256, 0, stream>>>(part, part2, st136, 136, 1024, 1024);
  wz_prep2<<<90, 256, 0, stream>>>(conv_z_w, wzb2);
  conv_z7_kernel<<<1024, 256, 0, stream>>>(z, alpha, st136, wzb2, conv_z_b, zout);
}

// Round 23
// 180.543 us; speedup vs baseline: 1.1264x; 1.0080x over previous
//
#include <hip/hip_runtime.h>
#include <math.h>

#define LLEN 256
#define NDIM 256
#define NHEAD 8
#define HDIM 32
#define NPIX (LLEN*LLEN)

typedef __bf16 bf16x8 __attribute__((ext_vector_type(8)));
typedef float f32x4 __attribute__((ext_vector_type(4)));

// ---- workspace layout (float offsets) ----
constexpr size_t OFF_Q     = 0;
constexpr size_t OFF_K     = 65536;
constexpr size_t OFF_V     = 131072;
constexpr size_t OFF_CAT16 = 196608;
constexpr size_t OFF_H1B   = 196608;
constexpr size_t OFF_W1B   = 360448;
constexpr size_t OFF_A1    = 1245184;   // transient: z-stats partials, then a1
constexpr size_t OFF_ALPHA = 1769472;
constexpr size_t OFF_AGG   = 2293760;
constexpr size_t OFF_Y     = 2621440;   // transient: cat16 stats partials, then y
constexpr size_t OFF_ST16  = 2752512;
constexpr size_t OFF_ST9   = 2752544;
constexpr size_t OFF_ST136 = 2752576;
constexpr size_t OFF_PART  = 2752864;
constexpr size_t OFF_PART2 = 2892128;
constexpr size_t OFF_WZB2  = 3031392;

__device__ inline unsigned short f2b(float x){
  union { float f; unsigned u; } a; a.f = x;
  unsigned r = a.u + 0x7fffu + ((a.u >> 16) & 1u);
  return (unsigned short)(r >> 16);
}

// ============ K1 v2: q,k,v = x @ W^T (4 rows/block, 192 blocks) ============
__global__ __launch_bounds__(256) void qkv2_kernel(
    const float* __restrict__ x, const float* __restrict__ Wq,
    const float* __restrict__ Wk, const float* __restrict__ Wv,
    float* __restrict__ q, float* __restrict__ k, float* __restrict__ v){
  __shared__ __align__(16) float xs[4][256];
  int t = threadIdx.x;
  int i0 = blockIdx.x * 4;
  int m = blockIdx.y;
  const float* W = (m==0)?Wq:((m==1)?Wk:Wv);
  float* out = (m==0)?q:((m==1)?k:v);
  for (int idx = t; idx < 1024; idx += 256)
    xs[idx>>8][idx&255] = x[(size_t)i0*256 + idx];
  __syncthreads();
  float acc[4];
  #pragma unroll
  for (int r = 0; r < 4; r++) acc[r] = 0.f;
  const float4* wr = (const float4*)(W + (size_t)t*256);
  for (int kk = 0; kk < 64; ++kk){
    float4 w4 = wr[kk];
    #pragma unroll
    for (int r = 0; r < 4; r++){
      float4 xv = ((const float4*)xs[r])[kk];
      acc[r] += w4.x*xv.x + w4.y*xv.y + w4.z*xv.z + w4.w*xv.w;
    }
  }
  #pragma unroll
  for (int r = 0; r < 4; r++) out[(size_t)(i0+r)*256 + t] = acc[r];
}

// ============ K2 v5: cat16 + fused cat16-stats + fused z-stats partials =====
__global__ __launch_bounds__(256) void cat16v5_kernel(
    const float* __restrict__ z, const float* __restrict__ qb,
    const float* __restrict__ kb, const float* __restrict__ Wp2a,
    float* __restrict__ cat16, float* __restrict__ p16, float* __restrict__ p16q,
    float* __restrict__ zpart, float* __restrict__ zpartq){
  __shared__ __align__(16) float zs2[32*132];
  __shared__ __align__(16) float ws2[8*132];
  __shared__ float sA[512];
  int t = threadIdx.x;
  int pix0 = blockIdx.x * 32;
  int i = pix0 >> 8;
  int j0 = pix0 & 255;
  { int h = t >> 5, j = t & 31;
    float4 v = *(const float4*)(Wp2a + h*128 + j*4);
    *(float4*)(ws2 + h*132 + j*4) = v; }
  #pragma unroll
  for (int k = 0; k < 4; ++k){
    int idx = t + k*256;
    int pix = idx >> 5, j = idx & 31;
    float4 v = *(const float4*)(z + ((size_t)(pix0 + pix))*128 + j*4);
    *(float4*)(zs2 + pix*132 + j*4) = v;
  }
  __syncthreads();
  int p8 = t >> 3, h = t & 7;
  const float* zr = zs2 + p8*132;
  const float* wr = ws2 + h*132;
  float ap = 0.f;
  #pragma unroll 8
  for (int j = 0; j < 32; ++j){
    float4 a = *(const float4*)(zr + j*4);
    float4 b = *(const float4*)(wr + j*4);
    ap += a.x*b.x + a.y*b.y + a.z*b.z + a.w*b.w;
  }
  const float* qg = qb + (size_t)i*256 + h*32;
  const float* kg = kb + (size_t)(j0 + p8)*256 + h*32;
  float an = 0.f;
  #pragma unroll
  for (int d4 = 0; d4 < 8; ++d4){
    float4 a = *(const float4*)(qg + d4*4);
    float4 b = *(const float4*)(kg + d4*4);
    an += a.x*b.x + a.y*b.y + a.z*b.z + a.w*b.w;
  }
  an *= 0.17677669529663689f;
  int pix = pix0 + p8;
  cat16[(size_t)pix*16 + h] = ap;
  cat16[(size_t)pix*16 + 8 + h] = an;
  sA[p8*16 + h] = ap;
  sA[p8*16 + 8 + h] = an;
  __syncthreads();
  if (t < 16){
    float S = 0.f, Q = 0.f;
    #pragma unroll
    for (int p = 0; p < 32; ++p){ float v = sA[p*16 + t]; S += v; Q += v*v; }
    p16 [(size_t)t*2048 + blockIdx.x] = S;
    p16q[(size_t)t*2048 + blockIdx.x] = Q;
  }
  // fused z-channel stats partials (channels 0..127) from the zs2 tile
  if (t < 128){
    float S = 0.f, Q = 0.f;
    #pragma unroll 8
    for (int p = 0; p < 32; ++p){ float v = zs2[p*132 + t]; S += v; Q += v*v; }
    zpart [(size_t)t*2048 + blockIdx.x] = S;
    zpartq[(size_t)t*2048 + blockIdx.x] = Q;
  }
}

__device__ inline void block_reduce2(float& s, float& s2, float* red){
  int t = threadIdx.x;
  int lane = t & 63, wv = t >> 6;
  #pragma unroll
  for (int o = 32; o > 0; o >>= 1){ s += __shfl_down(s, o); s2 += __shfl_down(s2, o); }
  __syncthreads();
  if (lane == 0){ red[wv] = s; red[4+wv] = s2; }
  __syncthreads();
  s  = red[0]+red[1]+red[2]+red[3];
  s2 = red[4]+red[5]+red[6]+red[7];
}

// stage B: reduce partials -> (mean, inv-std); stride+offset parameterized
__global__ __launch_bounds__(256) void statsB_kernel(
    const float* __restrict__ part, const float* __restrict__ part2,
    float* __restrict__ st, int C, int co, int nb, int stride){
  __shared__ float red[8];
  int c = blockIdx.x, t = threadIdx.x;
  float s = 0.f, q = 0.f;
  for (int i = t; i < nb; i += 256){
    s += part[(size_t)c*stride + i];
    q += part2[(size_t)c*stride + i];
  }
  block_reduce2(s, q, red);
  if (t == 0){
    float m = s * (1.f/NPIX);
    float var = q * (1.f/NPIX) - m*m;
    st[co + c] = m;
    st[C + co + c] = rsqrtf(var + 1e-5f);
  }
}

// ============ small conv 3x3 v6: fused output-stats partials ============
template<int CIN, int COUT, bool PL>
__global__ __launch_bounds__(256) void conv_small6_kernel(
    const float* __restrict__ A, int Ca, const float* __restrict__ B, int Cb,
    const float* __restrict__ st, const float* __restrict__ w,
    const float* __restrict__ bias, float* __restrict__ out,
    const float* __restrict__ plddt, float* __restrict__ part,
    float* __restrict__ part2, int coff){
  constexpr int WD = 67;
  __shared__ float xn[3][CIN][WD];
  __shared__ float wsm[COUT*CIN*9];
  __shared__ float ms[CIN], isd[CIN], bs[COUT];
  __shared__ float sB[COUT*64];
  __shared__ float sP[64];
  int t = threadIdx.x;
  int i = blockIdx.x >> 2, chb = blockIdx.x & 3;
  int c0 = chb*64;
  if (t < CIN){ ms[t] = st[t]; isd[t] = st[CIN + t]; }
  if (t < COUT) bs[t] = bias[t];
  for (int idx = t; idx < COUT*CIN*9; idx += 256) wsm[idx] = w[idx];
  __syncthreads();
  constexpr int TOT = 66*CIN;
  for (int s = 0; s < 3; ++s){
    int ir = i - 1 + s;
    for (int idx = t; idx < TOT; idx += 256){
      int col = idx / CIN, c = idx - col*CIN;
      int gcol = c0 + col - 1;
      float vv = 0.f;
      if (ir >= 0 && ir < 256 && gcol >= 0 && gcol < 256){
        size_t pix = (size_t)ir*256 + gcol;
        float raw = (c < Ca) ? A[pix*Ca + c] : B[pix*Cb + (c - Ca)];
        vv = (raw - ms[c]) * isd[c];
      }
      xn[s][c][col] = vv;
    }
  }
  __syncthreads();
  int os = t >> 6, tc = t & 63;
  float a0 = bs[os*2], a1 = bs[os*2 + 1];
  #pragma unroll
  for (int kh = 0; kh < 3; ++kh){
    #pragma unroll
    for (int c = 0; c < CIN; ++c){
      float x0 = xn[kh][c][tc];
      float x1 = xn[kh][c][tc + 1];
      float x2 = xn[kh][c][tc + 2];
      const float* w0 = wsm + (((os*2+0)*CIN + c)*3 + kh)*3;
      const float* w1 = wsm + (((os*2+1)*CIN + c)*3 + kh)*3;
      a0 += x0*w0[0] + x1*w0[1] + x2*w0[2];
      a1 += x0*w1[0] + x1*w1[1] + x2*w1[2];
    }
  }
  a0 = (a0 >= 0.f) ? a0 : 0.01f*a0;
  a1 = (a1 >= 0.f) ? a1 : 0.01f*a1;
  float2 v2 = { a0, a1 };
  *(float2*)(out + ((size_t)(i*256 + c0 + tc))*COUT + os*2) = v2;
  sB[os*128 + tc]      = a0;
  sB[os*128 + 64 + tc] = a1;
  if (PL && t < 64) sP[t] = plddt[(size_t)i*256 + c0 + t];
  __syncthreads();
  if (t < COUT){
    int os2 = t >> 1, par = t & 1;
    const float* src = sB + os2*128 + par*64;
    float S = 0.f, Q = 0.f;
    #pragma unroll
    for (int j = 0; j < 64; ++j){ float v = src[j]; S += v; Q += v*v; }
    part [(size_t)(coff + t)*1024 + blockIdx.x] = S;
    part2[(size_t)(coff + t)*1024 + blockIdx.x] = Q;
  } else if (PL && t == COUT){
    float S = 0.f, Q = 0.f;
    #pragma unroll
    for (int j = 0; j < 64; ++j){ float v = sP[j]; S += v; Q += v*v; }
    part [(size_t)(coff + COUT)*1024 + blockIdx.x] = S;
    part2[(size_t)(coff + COUT)*1024 + blockIdx.x] = Q;
  }
}

// ============ aggregation (512 thr, split-j, unrolled loads) ============
__global__ __launch_bounds__(512) void agg_kernel2(
    const float* __restrict__ alpha, const float* __restrict__ z,
    const float* __restrict__ v, float* __restrict__ agg){
  __shared__ float as[2048];
  __shared__ float pp[256][4];
  __shared__ float np[256];
  int i = blockIdx.x, t = threadIdx.x;
  for (int idx = t; idx < 2048; idx += 512) as[idx] = alpha[(size_t)i*2048 + idx];
  __syncthreads();
  int tt = t & 255, jh = t >> 8;
  int p = tt & 127, hh = tt >> 7;
  const float* zrow = z + (size_t)i*32768 + (size_t)jh*128*128;
  const float* ar0 = as + jh*128*8;
  float a0=0.f, a1=0.f, a2=0.f, a3=0.f;
  #pragma unroll 8
  for (int j = 0; j < 128; ++j){
    float zv = zrow[j*128 + p];
    const float* ar = ar0 + j*8 + hh*4;
    a0 += ar[0]*zv; a1 += ar[1]*zv; a2 += ar[2]*zv; a3 += ar[3]*zv;
  }
  int h = tt >> 5;
  float an = 0.f;
  const float* vrow = v + (size_t)jh*128*256;
  const float* ah0 = as + jh*128*8;
  #pragma unroll 8
  for (int j = 0; j < 128; ++j) an += ah0[j*8 + h]*vrow[j*256 + tt];
  if (jh == 1){
    pp[tt][0]=a0; pp[tt][1]=a1; pp[tt][2]=a2; pp[tt][3]=a3; np[tt]=an;
  }
  __syncthreads();
  if (jh == 0){
    a0 += pp[tt][0]; a1 += pp[tt][1]; a2 += pp[tt][2]; a3 += pp[tt][3];
    an += np[tt];
    size_t ob = (size_t)i*1280;
    agg[ob + (hh*4+0)*128 + p] = a0;
    agg[ob + (hh*4+1)*128 + p] = a1;
    agg[ob + (hh*4+2)*128 + p] = a2;
    agg[ob + (hh*4+3)*128 + p] = a3;
    agg[ob + 1024 + tt] = an;
  }
}

// ============ out_transform: LN1 -> bf16 ============
__global__ __launch_bounds__(256) void ln1_kernel(
    const float* __restrict__ agg,
    const float* __restrict__ ln1_g, const float* __restrict__ ln1_b,
    unsigned short* __restrict__ h1b){
  __shared__ float red[8];
  int i = blockIdx.x, t = threadIdx.x;
  float v[5], s = 0.f, s2 = 0.f;
  #pragma unroll
  for (int qq = 0; qq < 5; ++qq){
    v[qq] = agg[(size_t)i*1280 + qq*256 + t];
    s += v[qq]; s2 += v[qq]*v[qq];
  }
  block_reduce2(s, s2, red);
  float m = s*(1.f/1280.f), istd = rsqrtf(s2*(1.f/1280.f) - m*m + 1e-5f);
  #pragma unroll
  for (int qq = 0; qq < 5; ++qq){
    int kk = qq*256 + t;
    h1b[(size_t)i*1280 + kk] = f2b((v[qq] - m)*istd*ln1_g[kk] + ln1_b[kk]);
  }
}

// ============ prep: lin1_w -> bf16  +  conv_z weight pack (merged) ==========
__global__ __launch_bounds__(256) void prep_kernel(
    const float* __restrict__ lw, unsigned short* __restrict__ wb,
    const float* __restrict__ zw, unsigned short* __restrict__ wzb2){
  int bid = blockIdx.x;
  if (bid < 640){
    int idx = (bid*256 + threadIdx.x)*4;
    float4 v = *(const float4*)(lw + idx);
    ushort4 u;
    u.x = f2b(v.x); u.y = f2b(v.y); u.z = f2b(v.z); u.w = f2b(v.w);
    *(ushort4*)(wb + idx) = u;
  } else {
    int idx = (bid - 640)*256 + threadIdx.x;
    if (idx < 23040){
      int lane = idx & 63;
      int f = idx >> 6;
      int k = f % 5; int ft = f / 5; int tap = ft % 9; int ocb = ft / 9;
      int oc = ocb*16 + (lane & 15);
      int chb = k*32 + (lane >> 4)*8;
      unsigned short u[8];
      #pragma unroll
      for (int j = 0; j < 8; ++j){
        int ch = chb + j;
        float vv = (ch < 136) ? zw[(size_t)oc*1224 + ch*9 + tap] : 0.f;
        u[j] = f2b(vv);
      }
      uint4 pk;
      pk.x = (unsigned)u[0] | ((unsigned)u[1]<<16);
      pk.y = (unsigned)u[2] | ((unsigned)u[3]<<16);
      pk.z = (unsigned)u[4] | ((unsigned)u[5]<<16);
      pk.w = (unsigned)u[6] | ((unsigned)u[7]<<16);
      *(uint4*)(wzb2 + (size_t)idx*8) = pk;
    }
  }
}

// ============ gemm1: y[256x512] = h1b @ w1b^T + b, MFMA bf16 ============
__global__ __launch_bounds__(256) void gemm1_kernel(
    const unsigned short* __restrict__ h1b, const unsigned short* __restrict__ w1b,
    const float* __restrict__ lin1_b, float* __restrict__ y){
  int t = threadIdx.x;
  int mb = blockIdx.x & 3, nb = blockIdx.x >> 2;
  int lane = t & 63, w = t >> 6;
  int li = lane & 15, lg = lane >> 4;
  int mh = w & 1, nh = w >> 1;
  int mbase = mb*64 + mh*32, nbase = nb*64 + nh*32;
  f32x4 acc[2][2];
  #pragma unroll
  for (int a = 0; a < 2; ++a)
    #pragma unroll
    for (int b = 0; b < 2; ++b) acc[a][b] = (f32x4){0.f,0.f,0.f,0.f};
  const unsigned short* ar0 = h1b + (size_t)(mbase + li)*1280 + lg*8;
  const unsigned short* ar1 = ar0 + 16*1280;
  const unsigned short* br0 = w1b + (size_t)(nbase + li)*1280 + lg*8;
  const unsigned short* br1 = br0 + 16*1280;
  #pragma unroll 4
  for (int ks = 0; ks < 40; ++ks){
    bf16x8 a0 = *(const bf16x8*)(ar0 + ks*32);
    bf16x8 a1 = *(const bf16x8*)(ar1 + ks*32);
    bf16x8 b0 = *(const bf16x8*)(br0 + ks*32);
    bf16x8 b1 = *(const bf16x8*)(br1 + ks*32);
    acc[0][0] = __builtin_amdgcn_mfma_f32_16x16x32_bf16(a0, b0, acc[0][0], 0,0,0);
    acc[0][1] = __builtin_amdgcn_mfma_f32_16x16x32_bf16(a0, b1, acc[0][1], 0,0,0);
    acc[1][0] = __builtin_amdgcn_mfma_f32_16x16x32_bf16(a1, b0, acc[1][0], 0,0,0);
    acc[1][1] = __builtin_amdgcn_mfma_f32_16x16x32_bf16(a1, b1, acc[1][1], 0,0,0);
  }
  #pragma unroll
  for (int mi = 0; mi < 2; ++mi){
    #pragma unroll
    for (int ni = 0; ni < 2; ++ni){
      int col = nbase + ni*16 + li;
      float bb = lin1_b[col];
      #pragma unroll
      for (int ri = 0; ri < 4; ++ri){
        int row = mbase + mi*16 + lg*4 + ri;
        y[(size_t)row*512 + col] = acc[mi][ni][ri] + bb;
      }
    }
  }
}

// ============ outB v2: 2 rows/block ============
__global__ __launch_bounds__(256) void outB2_kernel(
    const float* __restrict__ y, const float* __restrict__ x,
    const float* __restrict__ ln2_g, const float* __restrict__ ln2_b,
    const float* __restrict__ lin2_w, const float* __restrict__ lin2_b,
    const float* __restrict__ lnf_g, const float* __restrict__ lnf_b,
    float* __restrict__ xout){
  __shared__ __align__(16) float h2[2][512];
  __shared__ float red[8];
  int t = threadIdx.x;
  int rb = blockIdx.x;
  for (int r = 0; r < 2; ++r){
    int i = rb*2 + r;
    float y0 = y[(size_t)i*512 + t], y1 = y[(size_t)i*512 + 256 + t];
    float s = y0 + y1, s2 = y0*y0 + y1*y1;
    block_reduce2(s, s2, red);
    float m = s*(1.f/512.f), istd = rsqrtf(s2*(1.f/512.f) - m*m + 1e-5f);
    float z0 = (y0 - m)*istd*ln2_g[t] + ln2_b[t];
    float z1 = (y1 - m)*istd*ln2_g[t+256] + ln2_b[t+256];
    h2[r][t]     = (z0 >= 0.f) ? z0 : 0.01f*z0;
    h2[r][t+256] = (z1 >= 0.f) ? z1 : 0.01f*z1;
  }
  __syncthreads();
  float acc[2];
  acc[0] = 0.f; acc[1] = 0.f;
  const float4* wr = (const float4*)(lin2_w + (size_t)t*512);
  #pragma unroll 4
  for (int kk = 0; kk < 128; ++kk){
    float4 w4 = wr[kk];
    #pragma unroll
    for (int r = 0; r < 2; ++r){
      float4 h = ((const float4*)h2[r])[kk];
      acc[r] += w4.x*h.x + w4.y*h.y + w4.z*h.z + w4.w*h.w;
    }
  }
  float bb = lin2_b[t];
  for (int r = 0; r < 2; ++r){
    int i = rb*2 + r;
    float xr = x[(size_t)i*256 + t] + acc[r] + bb;
    float s = xr, s2 = xr*xr;
    block_reduce2(s, s2, red);
    float m = s*(1.f/256.f), istd = rsqrtf(s2*(1.f/256.f) - m*m + 1e-5f);
    xout[(size_t)i*256 + t] = (xr - m)*istd*lnf_g[t] + lnf_b[t];
  }
}

// ============ conv_z v7: 2-row groups, small LDS (settled local optimum) =====
__global__ __launch_bounds__(256) void conv_z7_kernel(
    const float* __restrict__ z, const float* __restrict__ alpha,
    const float* __restrict__ st, const unsigned short* __restrict__ wzb2,
    const float* __restrict__ bias, float* __restrict__ out){
  __shared__ __align__(16) unsigned short xs[4*578*8];   // 18,496 B
  __shared__ float msp[153], isp[153];
  int t = threadIdx.x;
  int stripe = blockIdx.x & 7, rg = blockIdx.x >> 3;
  int i0 = rg*2, c0 = stripe*32;
  int lane = t & 63, w = t >> 6;
  int li = lane & 15, lg = lane >> 4;
  int wocb = w*2;
  if (t < 153){
    int cq = t/9, j = t - cq*9;
    bool vld = (j < 8);
    int ch = cq*8 + j;
    msp[t] = vld ? st[ch] : 0.f;
    isp[t] = vld ? st[136 + ch] : 0.f;
  }
  __syncthreads();
  for (int it = 0; it < 3; ++it){
    int cidx = t + it*256;
    int col = cidx / 17, cq = cidx - col*17;
    int gcol = c0 + col - 1;
    float mm[8], ss[8];
    #pragma unroll
    for (int j = 0; j < 8; ++j){ mm[j] = msp[cq*9 + j]; ss[j] = isp[cq*9 + j]; }
    if (cidx < 578){
      #pragma unroll
      for (int s = 0; s < 4; ++s){
        int ir = i0 - 1 + s;
        uint4 pk = {0u,0u,0u,0u};
        if (ir >= 0 && ir < 256 && gcol >= 0 && gcol < 256){
          const float* src = (cq < 16) ? (z + ((size_t)ir*256 + gcol)*128 + cq*8)
                                       : (alpha + ((size_t)ir*256 + gcol)*8);
          float4 r0 = *(const float4*)src;
          float4 r1 = *(const float4*)(src + 4);
          unsigned short u0 = f2b((r0.x - mm[0])*ss[0]);
          unsigned short u1 = f2b((r0.y - mm[1])*ss[1]);
          unsigned short u2 = f2b((r0.z - mm[2])*ss[2]);
          unsigned short u3 = f2b((r0.w - mm[3])*ss[3]);
          unsigned short u4 = f2b((r1.x - mm[4])*ss[4]);
          unsigned short u5 = f2b((r1.y - mm[5])*ss[5]);
          unsigned short u6 = f2b((r1.z - mm[6])*ss[6]);
          unsigned short u7 = f2b((r1.w - mm[7])*ss[7]);
          pk.x = (unsigned)u0 | ((unsigned)u1<<16);
          pk.y = (unsigned)u2 | ((unsigned)u3<<16);
          pk.z = (unsigned)u4 | ((unsigned)u5<<16);
          pk.w = (unsigned)u6 | ((unsigned)u7<<16);
        }
        *(uint4*)(xs + ((size_t)(s*578 + cidx))*8) = pk;
      }
    }
  }
  __syncthreads();

  f32x4 acc[2][2][2];
  #pragma unroll
  for (int r = 0; r < 2; ++r)
    #pragma unroll
    for (int m = 0; m < 2; ++m)
      #pragma unroll
      for (int o = 0; o < 2; ++o) acc[r][m][o] = (f32x4){0.f,0.f,0.f,0.f};

  for (int kh = 0; kh < 3; ++kh){
    for (int kw = 0; kw < 3; ++kw){
      int tap = kh*3 + kw;
      bf16x8 wf[5][2];
      #pragma unroll
      for (int k = 0; k < 5; ++k)
        #pragma unroll
        for (int o = 0; o < 2; ++o)
          wf[k][o] = *(const bf16x8*)(wzb2 + (size_t)((((wocb+o)*9 + tap)*5 + k)*64 + lane)*8);
      #pragma unroll
      for (int r = 0; r < 2; ++r){
        const unsigned short* sb = xs + (size_t)(r + kh)*578*8;
        #pragma unroll
        for (int k = 0; k < 5; ++k){
          int cq = (k < 4) ? (k*4 + lg) : 16;
          bf16x8 a0 = *(const bf16x8*)(sb + ((li+kw)*17 + cq)*8);
          bf16x8 a1 = *(const bf16x8*)(sb + ((li+kw+16)*17 + cq)*8);
          acc[r][0][0] = __builtin_amdgcn_mfma_f32_16x16x32_bf16(a0, wf[k][0], acc[r][0][0], 0,0,0);
          acc[r][0][1] = __builtin_amdgcn_mfma_f32_16x16x32_bf16(a0, wf[k][1], acc[r][0][1], 0,0,0);
          acc[r][1][0] = __builtin_amdgcn_mfma_f32_16x16x32_bf16(a1, wf[k][0], acc[r][1][0], 0,0,0);
          acc[r][1][1] = __builtin_amdgcn_mfma_f32_16x16x32_bf16(a1, wf[k][1], acc[r][1][1], 0,0,0);
        }
      }
    }
  }

  float b0 = bias[wocb*16 + li];
  float b1 = bias[(wocb+1)*16 + li];
  #pragma unroll
  for (int r = 0; r < 2; ++r){
    int i = i0 + r;
    #pragma unroll
    for (int m = 0; m < 2; ++m){
      #pragma unroll
      for (int ri = 0; ri < 4; ++ri){
        int px = m*16 + lg*4 + ri;
        size_t obase = ((size_t)(i*256 + c0 + px))*128;
        float v0 = acc[r][m][0][ri] + b0;
        float v1 = acc[r][m][1][ri] + b1;
        v0 = (v0 >= 0.f) ? v0 : 0.01f*v0;
        v1 = (v1 >= 0.f) ? v1 : 0.01f*v1;
        out[obase + wocb*16 + li]     = v0;
        out[obase + (wocb+1)*16 + li] = v1;
      }
    }
  }
}

extern "C" void kernel_launch(void* const* d_in, const int* in_sizes, int n_in,
                              void* d_out, int out_size, void* d_ws, size_t ws_size,
                              hipStream_t stream){
  const float* x        = (const float*)d_in[0];
  const float* z        = (const float*)d_in[1];
  const float* plddt    = (const float*)d_in[2];
  const float* Wq       = (const float*)d_in[3];
  const float* Wk       = (const float*)d_in[4];
  const float* Wv       = (const float*)d_in[5];
  const float* Wp2a     = (const float*)d_in[6];
  const float* conv_a_w = (const float*)d_in[7];
  const float* conv_a_b = (const float*)d_in[8];
  const float* conv_p_w = (const float*)d_in[9];
  const float* conv_p_b = (const float*)d_in[10];
  const float* ln1_g    = (const float*)d_in[11];
  const float* ln1_b    = (const float*)d_in[12];
  const float* lin1_w   = (const float*)d_in[13];
  const float* lin1_b   = (const float*)d_in[14];
  const float* ln2_g    = (const float*)d_in[15];
  const float* ln2_b    = (const float*)d_in[16];
  const float* lin2_w   = (const float*)d_in[17];
  const float* lin2_b   = (const float*)d_in[18];
  const float* lnf_g    = (const float*)d_in[19];
  const float* lnf_b    = (const float*)d_in[20];
  const float* conv_z_w = (const float*)d_in[21];
  const float* conv_z_b = (const float*)d_in[22];

  float* ws    = (float*)d_ws;
  float* q     = ws + OFF_Q;
  float* k     = ws + OFF_K;
  float* v     = ws + OFF_V;
  float* cat16 = ws + OFF_CAT16;
  float* a1    = ws + OFF_A1;
  float* zpart = ws + OFF_A1;            // transient: z stats partials
  float* zpartq= ws + OFF_A1 + 262144;   // (consumed before a1 is written)
  float* alpha = ws + OFF_ALPHA;
  float* agg   = ws + OFF_AGG;
  float* y     = ws + OFF_Y;
  float* p16   = ws + OFF_Y;             // transient: cat16 stats partials
  float* p16q  = ws + OFF_Y + 32768;     // (consumed before gemm1 writes y)
  float* st16  = ws + OFF_ST16;
  float* st9   = ws + OFF_ST9;
  float* st136 = ws + OFF_ST136;
  float* part  = ws + OFF_PART;
  float* part2 = ws + OFF_PART2;
  unsigned short* wzb2 = (unsigned short*)(ws + OFF_WZB2);
  unsigned short* h1b  = (unsigned short*)(ws + OFF_H1B);
  unsigned short* w1b  = (unsigned short*)(ws + OFF_W1B);

  float* xout = (float*)d_out;
  float* zout = (float*)d_out + 65536;

  qkv2_kernel<<<dim3(64,3), 256, 0, stream>>>(x, Wq, Wk, Wv, q, k, v);
  cat16v5_kernel<<<2048, 256, 0, stream>>>(z, q, k, Wp2a, cat16, p16, p16q,
                                           zpart, zpartq);
  statsB_kernel<<<16, 256, 0, stream>>>(p16, p16q, st16, 16, 0, 2048, 2048);
  // z-channel stats (st136 channels 0..127) from cat16-fused partials;
  // must run before conv_small6<16,8> overwrites the A1 region
  statsB_kernel<<<128, 256, 0, stream>>>(zpart, zpartq, st136, 136, 0, 2048, 2048);
  conv_small6_kernel<16,8,true><<<1024, 256, 0, stream>>>(
      cat16, 16, (const float*)nullptr, 0, st16, conv_a_w, conv_a_b, a1,
      plddt, part, part2, 0);
  statsB_kernel<<<9, 256, 0, stream>>>(part, part2, st9, 9, 0, 1024, 1024);
  conv_small6_kernel<9,8,false><<<1024, 256, 0, stream>>>(
      a1, 8, plddt, 1, st9, conv_p_w, conv_p_b, alpha,
      (const float*)nullptr, part, part2, 128);
  // alpha-channel stats (st136 channels 128..135) from conv-fused partials
  statsB_kernel<<<8, 256, 0, stream>>>(part + (size_t)128*1024,
                                       part2 + (size_t)128*1024,
                                       st136, 136, 128, 1024, 1024);
  agg_kernel2<<<256, 512, 0, stream>>>(alpha, z, v, agg);
  prep_kernel<<<730, 256, 0, stream>>>(lin1_w, w1b, conv_z_w, wzb2);
  ln1_kernel<<<256, 256, 0, stream>>>(agg, ln1_g, ln1_b, h1b);
  gemm1_kernel<<<32, 256, 0, stream>>>(h1b, w1b, lin1_b, y);
  outB2_kernel<<<128, 256, 0, stream>>>(y, x, ln2_g, ln2_b, lin2_w, lin2_b,
                                        lnf_g, lnf_b, xout);
  conv_z7_kernel<<<1024, 256, 0, stream>>>(z, alpha, st136, wzb2, conv_z_b, zout);
}

// Round 24
// 175.149 us; speedup vs baseline: 1.1611x; 1.0308x over previous
//
#include <hip/hip_runtime.h>
#include <math.h>

#define LLEN 256
#define NDIM 256
#define NHEAD 8
#define HDIM 32
#define NPIX (LLEN*LLEN)

typedef __bf16 bf16x8 __attribute__((ext_vector_type(8)));
typedef float f32x4 __attribute__((ext_vector_type(4)));

// ---- workspace layout (float offsets) ----
constexpr size_t OFF_Q     = 0;
constexpr size_t OFF_K     = 65536;
constexpr size_t OFF_V     = 131072;
constexpr size_t OFF_CAT16 = 196608;
constexpr size_t OFF_H1B   = 196608;
constexpr size_t OFF_W1B   = 360448;
constexpr size_t OFF_A1    = 1245184;   // transient: z-stats partials, then a1
constexpr size_t OFF_ALPHA = 1769472;
constexpr size_t OFF_AGG   = 2293760;   // (now unused by agg; spare)
constexpr size_t OFF_Y     = 2621440;   // transient: cat16 stats partials, then y
constexpr size_t OFF_ST16  = 2752512;
constexpr size_t OFF_ST9   = 2752544;
constexpr size_t OFF_ST136 = 2752576;
constexpr size_t OFF_PART  = 2752864;
constexpr size_t OFF_PART2 = 2892128;
constexpr size_t OFF_WZB2  = 3031392;

__device__ inline unsigned short f2b(float x){
  union { float f; unsigned u; } a; a.f = x;
  unsigned r = a.u + 0x7fffu + ((a.u >> 16) & 1u);
  return (unsigned short)(r >> 16);
}

// ============ K1 v2: q,k,v = x @ W^T (4 rows/block, 192 blocks) ============
__global__ __launch_bounds__(256) void qkv2_kernel(
    const float* __restrict__ x, const float* __restrict__ Wq,
    const float* __restrict__ Wk, const float* __restrict__ Wv,
    float* __restrict__ q, float* __restrict__ k, float* __restrict__ v){
  __shared__ __align__(16) float xs[4][256];
  int t = threadIdx.x;
  int i0 = blockIdx.x * 4;
  int m = blockIdx.y;
  const float* W = (m==0)?Wq:((m==1)?Wk:Wv);
  float* out = (m==0)?q:((m==1)?k:v);
  for (int idx = t; idx < 1024; idx += 256)
    xs[idx>>8][idx&255] = x[(size_t)i0*256 + idx];
  __syncthreads();
  float acc[4];
  #pragma unroll
  for (int r = 0; r < 4; r++) acc[r] = 0.f;
  const float4* wr = (const float4*)(W + (size_t)t*256);
  for (int kk = 0; kk < 64; ++kk){
    float4 w4 = wr[kk];
    #pragma unroll
    for (int r = 0; r < 4; r++){
      float4 xv = ((const float4*)xs[r])[kk];
      acc[r] += w4.x*xv.x + w4.y*xv.y + w4.z*xv.z + w4.w*xv.w;
    }
  }
  #pragma unroll
  for (int r = 0; r < 4; r++) out[(size_t)(i0+r)*256 + t] = acc[r];
}

// ============ K2 v5: cat16 + fused cat16-stats + fused z-stats partials =====
__global__ __launch_bounds__(256) void cat16v5_kernel(
    const float* __restrict__ z, const float* __restrict__ qb,
    const float* __restrict__ kb, const float* __restrict__ Wp2a,
    float* __restrict__ cat16, float* __restrict__ p16, float* __restrict__ p16q,
    float* __restrict__ zpart, float* __restrict__ zpartq){
  __shared__ __align__(16) float zs2[32*132];
  __shared__ __align__(16) float ws2[8*132];
  __shared__ float sA[512];
  int t = threadIdx.x;
  int pix0 = blockIdx.x * 32;
  int i = pix0 >> 8;
  int j0 = pix0 & 255;
  { int h = t >> 5, j = t & 31;
    float4 v = *(const float4*)(Wp2a + h*128 + j*4);
    *(float4*)(ws2 + h*132 + j*4) = v; }
  #pragma unroll
  for (int k = 0; k < 4; ++k){
    int idx = t + k*256;
    int pix = idx >> 5, j = idx & 31;
    float4 v = *(const float4*)(z + ((size_t)(pix0 + pix))*128 + j*4);
    *(float4*)(zs2 + pix*132 + j*4) = v;
  }
  __syncthreads();
  int p8 = t >> 3, h = t & 7;
  const float* zr = zs2 + p8*132;
  const float* wr = ws2 + h*132;
  float ap = 0.f;
  #pragma unroll 8
  for (int j = 0; j < 32; ++j){
    float4 a = *(const float4*)(zr + j*4);
    float4 b = *(const float4*)(wr + j*4);
    ap += a.x*b.x + a.y*b.y + a.z*b.z + a.w*b.w;
  }
  const float* qg = qb + (size_t)i*256 + h*32;
  const float* kg = kb + (size_t)(j0 + p8)*256 + h*32;
  float an = 0.f;
  #pragma unroll
  for (int d4 = 0; d4 < 8; ++d4){
    float4 a = *(const float4*)(qg + d4*4);
    float4 b = *(const float4*)(kg + d4*4);
    an += a.x*b.x + a.y*b.y + a.z*b.z + a.w*b.w;
  }
  an *= 0.17677669529663689f;
  int pix = pix0 + p8;
  cat16[(size_t)pix*16 + h] = ap;
  cat16[(size_t)pix*16 + 8 + h] = an;
  sA[p8*16 + h] = ap;
  sA[p8*16 + 8 + h] = an;
  __syncthreads();
  if (t < 16){
    float S = 0.f, Q = 0.f;
    #pragma unroll
    for (int p = 0; p < 32; ++p){ float v = sA[p*16 + t]; S += v; Q += v*v; }
    p16 [(size_t)t*2048 + blockIdx.x] = S;
    p16q[(size_t)t*2048 + blockIdx.x] = Q;
  }
  if (t < 128){
    float S = 0.f, Q = 0.f;
    #pragma unroll 8
    for (int p = 0; p < 32; ++p){ float v = zs2[p*132 + t]; S += v; Q += v*v; }
    zpart [(size_t)t*2048 + blockIdx.x] = S;
    zpartq[(size_t)t*2048 + blockIdx.x] = Q;
  }
}

__device__ inline void block_reduce2(float& s, float& s2, float* red){
  int t = threadIdx.x;
  int lane = t & 63, wv = t >> 6;
  #pragma unroll
  for (int o = 32; o > 0; o >>= 1){ s += __shfl_down(s, o); s2 += __shfl_down(s2, o); }
  __syncthreads();
  if (lane == 0){ red[wv] = s; red[4+wv] = s2; }
  __syncthreads();
  s  = red[0]+red[1]+red[2]+red[3];
  s2 = red[4]+red[5]+red[6]+red[7];
}

// 512-thread variant (8 waves): separate slot banks to avoid collision
__device__ inline void block_reduce2_512(float& s, float& s2, float* red16){
  int t = threadIdx.x;
  int lane = t & 63, wv = t >> 6;   // wv 0..7
  #pragma unroll
  for (int o = 32; o > 0; o >>= 1){ s += __shfl_down(s, o); s2 += __shfl_down(s2, o); }
  __syncthreads();
  if (lane == 0){ red16[wv] = s; red16[8+wv] = s2; }
  __syncthreads();
  s = 0.f; s2 = 0.f;
  #pragma unroll
  for (int j = 0; j < 8; ++j){ s += red16[j]; s2 += red16[8+j]; }
}

// stage B: reduce partials -> (mean, inv-std); stride+offset parameterized
__global__ __launch_bounds__(256) void statsB_kernel(
    const float* __restrict__ part, const float* __restrict__ part2,
    float* __restrict__ st, int C, int co, int nb, int stride){
  __shared__ float red[8];
  int c = blockIdx.x, t = threadIdx.x;
  float s = 0.f, q = 0.f;
  for (int i = t; i < nb; i += 256){
    s += part[(size_t)c*stride + i];
    q += part2[(size_t)c*stride + i];
  }
  block_reduce2(s, q, red);
  if (t == 0){
    float m = s * (1.f/NPIX);
    float var = q * (1.f/NPIX) - m*m;
    st[co + c] = m;
    st[C + co + c] = rsqrtf(var + 1e-5f);
  }
}

// merged stage B: blocks 0..15 -> st16; blocks 16..143 -> st136[0..127]
__global__ __launch_bounds__(256) void statsB2_kernel(
    const float* __restrict__ p16, const float* __restrict__ p16q,
    float* __restrict__ st16,
    const float* __restrict__ zpart, const float* __restrict__ zpartq,
    float* __restrict__ st136){
  __shared__ float red[8];
  int b = blockIdx.x, t = threadIdx.x;
  const float* P; const float* Q; float* st; int C, c;
  if (b < 16){ P = p16; Q = p16q; st = st16; C = 16; c = b; }
  else       { P = zpart; Q = zpartq; st = st136; C = 136; c = b - 16; }
  float s = 0.f, q = 0.f;
  for (int i = t; i < 2048; i += 256){
    s += P[(size_t)c*2048 + i];
    q += Q[(size_t)c*2048 + i];
  }
  block_reduce2(s, q, red);
  if (t == 0){
    float m = s * (1.f/NPIX);
    float var = q * (1.f/NPIX) - m*m;
    st[c] = m;
    st[C + c] = rsqrtf(var + 1e-5f);
  }
}

// ============ small conv 3x3 v6: fused output-stats partials ============
template<int CIN, int COUT, bool PL>
__global__ __launch_bounds__(256) void conv_small6_kernel(
    const float* __restrict__ A, int Ca, const float* __restrict__ B, int Cb,
    const float* __restrict__ st, const float* __restrict__ w,
    const float* __restrict__ bias, float* __restrict__ out,
    const float* __restrict__ plddt, float* __restrict__ part,
    float* __restrict__ part2, int coff){
  constexpr int WD = 67;
  __shared__ float xn[3][CIN][WD];
  __shared__ float wsm[COUT*CIN*9];
  __shared__ float ms[CIN], isd[CIN], bs[COUT];
  __shared__ float sB[COUT*64];
  __shared__ float sP[64];
  int t = threadIdx.x;
  int i = blockIdx.x >> 2, chb = blockIdx.x & 3;
  int c0 = chb*64;
  if (t < CIN){ ms[t] = st[t]; isd[t] = st[CIN + t]; }
  if (t < COUT) bs[t] = bias[t];
  for (int idx = t; idx < COUT*CIN*9; idx += 256) wsm[idx] = w[idx];
  __syncthreads();
  constexpr int TOT = 66*CIN;
  for (int s = 0; s < 3; ++s){
    int ir = i - 1 + s;
    for (int idx = t; idx < TOT; idx += 256){
      int col = idx / CIN, c = idx - col*CIN;
      int gcol = c0 + col - 1;
      float vv = 0.f;
      if (ir >= 0 && ir < 256 && gcol >= 0 && gcol < 256){
        size_t pix = (size_t)ir*256 + gcol;
        float raw = (c < Ca) ? A[pix*Ca + c] : B[pix*Cb + (c - Ca)];
        vv = (raw - ms[c]) * isd[c];
      }
      xn[s][c][col] = vv;
    }
  }
  __syncthreads();
  int os = t >> 6, tc = t & 63;
  float a0 = bs[os*2], a1 = bs[os*2 + 1];
  #pragma unroll
  for (int kh = 0; kh < 3; ++kh){
    #pragma unroll
    for (int c = 0; c < CIN; ++c){
      float x0 = xn[kh][c][tc];
      float x1 = xn[kh][c][tc + 1];
      float x2 = xn[kh][c][tc + 2];
      const float* w0 = wsm + (((os*2+0)*CIN + c)*3 + kh)*3;
      const float* w1 = wsm + (((os*2+1)*CIN + c)*3 + kh)*3;
      a0 += x0*w0[0] + x1*w0[1] + x2*w0[2];
      a1 += x0*w1[0] + x1*w1[1] + x2*w1[2];
    }
  }
  a0 = (a0 >= 0.f) ? a0 : 0.01f*a0;
  a1 = (a1 >= 0.f) ? a1 : 0.01f*a1;
  float2 v2 = { a0, a1 };
  *(float2*)(out + ((size_t)(i*256 + c0 + tc))*COUT + os*2) = v2;
  sB[os*128 + tc]      = a0;
  sB[os*128 + 64 + tc] = a1;
  if (PL && t < 64) sP[t] = plddt[(size_t)i*256 + c0 + t];
  __syncthreads();
  if (t < COUT){
    int os2 = t >> 1, par = t & 1;
    const float* src = sB + os2*128 + par*64;
    float S = 0.f, Q = 0.f;
    #pragma unroll
    for (int j = 0; j < 64; ++j){ float v = src[j]; S += v; Q += v*v; }
    part [(size_t)(coff + t)*1024 + blockIdx.x] = S;
    part2[(size_t)(coff + t)*1024 + blockIdx.x] = Q;
  } else if (PL && t == COUT){
    float S = 0.f, Q = 0.f;
    #pragma unroll
    for (int j = 0; j < 64; ++j){ float v = sP[j]; S += v; Q += v*v; }
    part [(size_t)(coff + COUT)*1024 + blockIdx.x] = S;
    part2[(size_t)(coff + COUT)*1024 + blockIdx.x] = Q;
  }
}

// ============ agg + fused LN1 -> h1b bf16 (512 thr, split-j) ============
__global__ __launch_bounds__(512) void agg_ln1_kernel(
    const float* __restrict__ alpha, const float* __restrict__ z,
    const float* __restrict__ v,
    const float* __restrict__ ln1_g, const float* __restrict__ ln1_b,
    unsigned short* __restrict__ h1b){
  __shared__ float as[2048];
  __shared__ float pp[256][4];
  __shared__ float np[256];
  __shared__ float red16[16];
  int i = blockIdx.x, t = threadIdx.x;
  for (int idx = t; idx < 2048; idx += 512) as[idx] = alpha[(size_t)i*2048 + idx];
  __syncthreads();
  int tt = t & 255, jh = t >> 8;
  int p = tt & 127, hh = tt >> 7;
  const float* zrow = z + (size_t)i*32768 + (size_t)jh*128*128;
  const float* ar0 = as + jh*128*8;
  float a0=0.f, a1=0.f, a2=0.f, a3=0.f;
  #pragma unroll 8
  for (int j = 0; j < 128; ++j){
    float zv = zrow[j*128 + p];
    const float* ar = ar0 + j*8 + hh*4;
    a0 += ar[0]*zv; a1 += ar[1]*zv; a2 += ar[2]*zv; a3 += ar[3]*zv;
  }
  int h = tt >> 5;
  float an = 0.f;
  const float* vrow = v + (size_t)jh*128*256;
  const float* ah0 = as + jh*128*8;
  #pragma unroll 8
  for (int j = 0; j < 128; ++j) an += ah0[j*8 + h]*vrow[j*256 + tt];
  if (jh == 1){
    pp[tt][0]=a0; pp[tt][1]=a1; pp[tt][2]=a2; pp[tt][3]=a3; np[tt]=an;
  }
  __syncthreads();
  float s = 0.f, s2 = 0.f;
  if (jh == 0){
    a0 += pp[tt][0]; a1 += pp[tt][1]; a2 += pp[tt][2]; a3 += pp[tt][3];
    an += np[tt];
    s  = a0 + a1 + a2 + a3 + an;
    s2 = a0*a0 + a1*a1 + a2*a2 + a3*a3 + an*an;
  }
  block_reduce2_512(s, s2, red16);
  float m = s*(1.f/1280.f), istd = rsqrtf(s2*(1.f/1280.f) - m*m + 1e-5f);
  if (jh == 0){
    size_t ob = (size_t)i*1280;
    int k0 = (hh*4+0)*128 + p;
    int k1 = (hh*4+1)*128 + p;
    int k2 = (hh*4+2)*128 + p;
    int k3 = (hh*4+3)*128 + p;
    int k4 = 1024 + tt;
    h1b[ob + k0] = f2b((a0 - m)*istd*ln1_g[k0] + ln1_b[k0]);
    h1b[ob + k1] = f2b((a1 - m)*istd*ln1_g[k1] + ln1_b[k1]);
    h1b[ob + k2] = f2b((a2 - m)*istd*ln1_g[k2] + ln1_b[k2]);
    h1b[ob + k3] = f2b((a3 - m)*istd*ln1_g[k3] + ln1_b[k3]);
    h1b[ob + k4] = f2b((an - m)*istd*ln1_g[k4] + ln1_b[k4]);
  }
}

// ============ prep: lin1_w -> bf16  +  conv_z weight pack (merged) ==========
__global__ __launch_bounds__(256) void prep_kernel(
    const float* __restrict__ lw, unsigned short* __restrict__ wb,
    const float* __restrict__ zw, unsigned short* __restrict__ wzb2){
  int bid = blockIdx.x;
  if (bid < 640){
    int idx = (bid*256 + threadIdx.x)*4;
    float4 v = *(const float4*)(lw + idx);
    ushort4 u;
    u.x = f2b(v.x); u.y = f2b(v.y); u.z = f2b(v.z); u.w = f2b(v.w);
    *(ushort4*)(wb + idx) = u;
  } else {
    int idx = (bid - 640)*256 + threadIdx.x;
    if (idx < 23040){
      int lane = idx & 63;
      int f = idx >> 6;
      int k = f % 5; int ft = f / 5; int tap = ft % 9; int ocb = ft / 9;
      int oc = ocb*16 + (lane & 15);
      int chb = k*32 + (lane >> 4)*8;
      unsigned short u[8];
      #pragma unroll
      for (int j = 0; j < 8; ++j){
        int ch = chb + j;
        float vv = (ch < 136) ? zw[(size_t)oc*1224 + ch*9 + tap] : 0.f;
        u[j] = f2b(vv);
      }
      uint4 pk;
      pk.x = (unsigned)u[0] | ((unsigned)u[1]<<16);
      pk.y = (unsigned)u[2] | ((unsigned)u[3]<<16);
      pk.z = (unsigned)u[4] | ((unsigned)u[5]<<16);
      pk.w = (unsigned)u[6] | ((unsigned)u[7]<<16);
      *(uint4*)(wzb2 + (size_t)idx*8) = pk;
    }
  }
}

// ============ gemm1: y[256x512] = h1b @ w1b^T + b, MFMA bf16 ============
__global__ __launch_bounds__(256) void gemm1_kernel(
    const unsigned short* __restrict__ h1b, const unsigned short* __restrict__ w1b,
    const float* __restrict__ lin1_b, float* __restrict__ y){
  int t = threadIdx.x;
  int mb = blockIdx.x & 3, nb = blockIdx.x >> 2;
  int lane = t & 63, w = t >> 6;
  int li = lane & 15, lg = lane >> 4;
  int mh = w & 1, nh = w >> 1;
  int mbase = mb*64 + mh*32, nbase = nb*64 + nh*32;
  f32x4 acc[2][2];
  #pragma unroll
  for (int a = 0; a < 2; ++a)
    #pragma unroll
    for (int b = 0; b < 2; ++b) acc[a][b] = (f32x4){0.f,0.f,0.f,0.f};
  const unsigned short* ar0 = h1b + (size_t)(mbase + li)*1280 + lg*8;
  const unsigned short* ar1 = ar0 + 16*1280;
  const unsigned short* br0 = w1b + (size_t)(nbase + li)*1280 + lg*8;
  const unsigned short* br1 = br0 + 16*1280;
  #pragma unroll 4
  for (int ks = 0; ks < 40; ++ks){
    bf16x8 a0 = *(const bf16x8*)(ar0 + ks*32);
    bf16x8 a1 = *(const bf16x8*)(ar1 + ks*32);
    bf16x8 b0 = *(const bf16x8*)(br0 + ks*32);
    bf16x8 b1 = *(const bf16x8*)(br1 + ks*32);
    acc[0][0] = __builtin_amdgcn_mfma_f32_16x16x32_bf16(a0, b0, acc[0][0], 0,0,0);
    acc[0][1] = __builtin_amdgcn_mfma_f32_16x16x32_bf16(a0, b1, acc[0][1], 0,0,0);
    acc[1][0] = __builtin_amdgcn_mfma_f32_16x16x32_bf16(a1, b0, acc[1][0], 0,0,0);
    acc[1][1] = __builtin_amdgcn_mfma_f32_16x16x32_bf16(a1, b1, acc[1][1], 0,0,0);
  }
  #pragma unroll
  for (int mi = 0; mi < 2; ++mi){
    #pragma unroll
    for (int ni = 0; ni < 2; ++ni){
      int col = nbase + ni*16 + li;
      float bb = lin1_b[col];
      #pragma unroll
      for (int ri = 0; ri < 4; ++ri){
        int row = mbase + mi*16 + lg*4 + ri;
        y[(size_t)row*512 + col] = acc[mi][ni][ri] + bb;
      }
    }
  }
}

// ============ outB v2: 2 rows/block ============
__global__ __launch_bounds__(256) void outB2_kernel(
    const float* __restrict__ y, const float* __restrict__ x,
    const float* __restrict__ ln2_g, const float* __restrict__ ln2_b,
    const float* __restrict__ lin2_w, const float* __restrict__ lin2_b,
    const float* __restrict__ lnf_g, const float* __restrict__ lnf_b,
    float* __restrict__ xout){
  __shared__ __align__(16) float h2[2][512];
  __shared__ float red[8];
  int t = threadIdx.x;
  int rb = blockIdx.x;
  for (int r = 0; r < 2; ++r){
    int i = rb*2 + r;
    float y0 = y[(size_t)i*512 + t], y1 = y[(size_t)i*512 + 256 + t];
    float s = y0 + y1, s2 = y0*y0 + y1*y1;
    block_reduce2(s, s2, red);
    float m = s*(1.f/512.f), istd = rsqrtf(s2*(1.f/512.f) - m*m + 1e-5f);
    float z0 = (y0 - m)*istd*ln2_g[t] + ln2_b[t];
    float z1 = (y1 - m)*istd*ln2_g[t+256] + ln2_b[t+256];
    h2[r][t]     = (z0 >= 0.f) ? z0 : 0.01f*z0;
    h2[r][t+256] = (z1 >= 0.f) ? z1 : 0.01f*z1;
  }
  __syncthreads();
  float acc[2];
  acc[0] = 0.f; acc[1] = 0.f;
  const float4* wr = (const float4*)(lin2_w + (size_t)t*512);
  #pragma unroll 4
  for (int kk = 0; kk < 128; ++kk){
    float4 w4 = wr[kk];
    #pragma unroll
    for (int r = 0; r < 2; ++r){
      float4 h = ((const float4*)h2[r])[kk];
      acc[r] += w4.x*h.x + w4.y*h.y + w4.z*h.z + w4.w*h.w;
    }
  }
  float bb = lin2_b[t];
  for (int r = 0; r < 2; ++r){
    int i = rb*2 + r;
    float xr = x[(size_t)i*256 + t] + acc[r] + bb;
    float s = xr, s2 = xr*xr;
    block_reduce2(s, s2, red);
    float m = s*(1.f/256.f), istd = rsqrtf(s2*(1.f/256.f) - m*m + 1e-5f);
    xout[(size_t)i*256 + t] = (xr - m)*istd*lnf_g[t] + lnf_b[t];
  }
}

// ============ conv_z v7: 2-row groups, small LDS (settled local optimum) =====
__global__ __launch_bounds__(256) void conv_z7_kernel(
    const float* __restrict__ z, const float* __restrict__ alpha,
    const float* __restrict__ st, const unsigned short* __restrict__ wzb2,
    const float* __restrict__ bias, float* __restrict__ out){
  __shared__ __align__(16) unsigned short xs[4*578*8];   // 18,496 B
  __shared__ float msp[153], isp[153];
  int t = threadIdx.x;
  int stripe = blockIdx.x & 7, rg = blockIdx.x >> 3;
  int i0 = rg*2, c0 = stripe*32;
  int lane = t & 63, w = t >> 6;
  int li = lane & 15, lg = lane >> 4;
  int wocb = w*2;
  if (t < 153){
    int cq = t/9, j = t - cq*9;
    bool vld = (j < 8);
    int ch = cq*8 + j;
    msp[t] = vld ? st[ch] : 0.f;
    isp[t] = vld ? st[136 + ch] : 0.f;
  }
  __syncthreads();
  for (int it = 0; it < 3; ++it){
    int cidx = t + it*256;
    int col = cidx / 17, cq = cidx - col*17;
    int gcol = c0 + col - 1;
    float mm[8], ss[8];
    #pragma unroll
    for (int j = 0; j < 8; ++j){ mm[j] = msp[cq*9 + j]; ss[j] = isp[cq*9 + j]; }
    if (cidx < 578){
      #pragma unroll
      for (int s = 0; s < 4; ++s){
        int ir = i0 - 1 + s;
        uint4 pk = {0u,0u,0u,0u};
        if (ir >= 0 && ir < 256 && gcol >= 0 && gcol < 256){
          const float* src = (cq < 16) ? (z + ((size_t)ir*256 + gcol)*128 + cq*8)
                                       : (alpha + ((size_t)ir*256 + gcol)*8);
          float4 r0 = *(const float4*)src;
          float4 r1 = *(const float4*)(src + 4);
          unsigned short u0 = f2b((r0.x - mm[0])*ss[0]);
          unsigned short u1 = f2b((r0.y - mm[1])*ss[1]);
          unsigned short u2 = f2b((r0.z - mm[2])*ss[2]);
          unsigned short u3 = f2b((r0.w - mm[3])*ss[3]);
          unsigned short u4 = f2b((r1.x - mm[4])*ss[4]);
          unsigned short u5 = f2b((r1.y - mm[5])*ss[5]);
          unsigned short u6 = f2b((r1.z - mm[6])*ss[6]);
          unsigned short u7 = f2b((r1.w - mm[7])*ss[7]);
          pk.x = (unsigned)u0 | ((unsigned)u1<<16);
          pk.y = (unsigned)u2 | ((unsigned)u3<<16);
          pk.z = (unsigned)u4 | ((unsigned)u5<<16);
          pk.w = (unsigned)u6 | ((unsigned)u7<<16);
        }
        *(uint4*)(xs + ((size_t)(s*578 + cidx))*8) = pk;
      }
    }
  }
  __syncthreads();

  f32x4 acc[2][2][2];
  #pragma unroll
  for (int r = 0; r < 2; ++r)
    #pragma unroll
    for (int m = 0; m < 2; ++m)
      #pragma unroll
      for (int o = 0; o < 2; ++o) acc[r][m][o] = (f32x4){0.f,0.f,0.f,0.f};

  for (int kh = 0; kh < 3; ++kh){
    for (int kw = 0; kw < 3; ++kw){
      int tap = kh*3 + kw;
      bf16x8 wf[5][2];
      #pragma unroll
      for (int k = 0; k < 5; ++k)
        #pragma unroll
        for (int o = 0; o < 2; ++o)
          wf[k][o] = *(const bf16x8*)(wzb2 + (size_t)((((wocb+o)*9 + tap)*5 + k)*64 + lane)*8);
      #pragma unroll
      for (int r = 0; r < 2; ++r){
        const unsigned short* sb = xs + (size_t)(r + kh)*578*8;
        #pragma unroll
        for (int k = 0; k < 5; ++k){
          int cq = (k < 4) ? (k*4 + lg) : 16;
          bf16x8 a0 = *(const bf16x8*)(sb + ((li+kw)*17 + cq)*8);
          bf16x8 a1 = *(const bf16x8*)(sb + ((li+kw+16)*17 + cq)*8);
          acc[r][0][0] = __builtin_amdgcn_mfma_f32_16x16x32_bf16(a0, wf[k][0], acc[r][0][0], 0,0,0);
          acc[r][0][1] = __builtin_amdgcn_mfma_f32_16x16x32_bf16(a0, wf[k][1], acc[r][0][1], 0,0,0);
          acc[r][1][0] = __builtin_amdgcn_mfma_f32_16x16x32_bf16(a1, wf[k][0], acc[r][1][0], 0,0,0);
          acc[r][1][1] = __builtin_amdgcn_mfma_f32_16x16x32_bf16(a1, wf[k][1], acc[r][1][1], 0,0,0);
        }
      }
    }
  }

  float b0 = bias[wocb*16 + li];
  float b1 = bias[(wocb+1)*16 + li];
  #pragma unroll
  for (int r = 0; r < 2; ++r){
    int i = i0 + r;
    #pragma unroll
    for (int m = 0; m < 2; ++m){
      #pragma unroll
      for (int ri = 0; ri < 4; ++ri){
        int px = m*16 + lg*4 + ri;
        size_t obase = ((size_t)(i*256 + c0 + px))*128;
        float v0 = acc[r][m][0][ri] + b0;
        float v1 = acc[r][m][1][ri] + b1;
        v0 = (v0 >= 0.f) ? v0 : 0.01f*v0;
        v1 = (v1 >= 0.f) ? v1 : 0.01f*v1;
        out[obase + wocb*16 + li]     = v0;
        out[obase + (wocb+1)*16 + li] = v1;
      }
    }
  }
}

extern "C" void kernel_launch(void* const* d_in, const int* in_sizes, int n_in,
                              void* d_out, int out_size, void* d_ws, size_t ws_size,
                              hipStream_t stream){
  const float* x        = (const float*)d_in[0];
  const float* z        = (const float*)d_in[1];
  const float* plddt    = (const float*)d_in[2];
  const float* Wq       = (const float*)d_in[3];
  const float* Wk       = (const float*)d_in[4];
  const float* Wv       = (const float*)d_in[5];
  const float* Wp2a     = (const float*)d_in[6];
  const float* conv_a_w = (const float*)d_in[7];
  const float* conv_a_b = (const float*)d_in[8];
  const float* conv_p_w = (const float*)d_in[9];
  const float* conv_p_b = (const float*)d_in[10];
  const float* ln1_g    = (const float*)d_in[11];
  const float* ln1_b    = (const float*)d_in[12];
  const float* lin1_w   = (const float*)d_in[13];
  const float* lin1_b   = (const float*)d_in[14];
  const float* ln2_g    = (const float*)d_in[15];
  const float* ln2_b    = (const float*)d_in[16];
  const float* lin2_w   = (const float*)d_in[17];
  const float* lin2_b   = (const float*)d_in[18];
  const float* lnf_g    = (const float*)d_in[19];
  const float* lnf_b    = (const float*)d_in[20];
  const float* conv_z_w = (const float*)d_in[21];
  const float* conv_z_b = (const float*)d_in[22];

  float* ws    = (float*)d_ws;
  float* q     = ws + OFF_Q;
  float* k     = ws + OFF_K;
  float* v     = ws + OFF_V;
  float* cat16 = ws + OFF_CAT16;
  float* a1    = ws + OFF_A1;
  float* zpart = ws + OFF_A1;            // transient: z stats partials
  float* zpartq= ws + OFF_A1 + 262144;   // (consumed before a1 is written)
  float* alpha = ws + OFF_ALPHA;
  float* y     = ws + OFF_Y;
  float* p16   = ws + OFF_Y;             // transient: cat16 stats partials
  float* p16q  = ws + OFF_Y + 32768;     // (consumed before gemm1 writes y)
  float* st16  = ws + OFF_ST16;
  float* st9   = ws + OFF_ST9;
  float* st136 = ws + OFF_ST136;
  float* part  = ws + OFF_PART;
  float* part2 = ws + OFF_PART2;
  unsigned short* wzb2 = (unsigned short*)(ws + OFF_WZB2);
  unsigned short* h1b  = (unsigned short*)(ws + OFF_H1B);
  unsigned short* w1b  = (unsigned short*)(ws + OFF_W1B);

  float* xout = (float*)d_out;
  float* zout = (float*)d_out + 65536;

  qkv2_kernel<<<dim3(64,3), 256, 0, stream>>>(x, Wq, Wk, Wv, q, k, v);
  cat16v5_kernel<<<2048, 256, 0, stream>>>(z, q, k, Wp2a, cat16, p16, p16q,
                                           zpart, zpartq);
  // merged: st16 (16 ch) + st136 z-channels (128 ch); before A1/Y are reused
  statsB2_kernel<<<144, 256, 0, stream>>>(p16, p16q, st16, zpart, zpartq, st136);
  conv_small6_kernel<16,8,true><<<1024, 256, 0, stream>>>(
      cat16, 16, (const float*)nullptr, 0, st16, conv_a_w, conv_a_b, a1,
      plddt, part, part2, 0);
  statsB_kernel<<<9, 256, 0, stream>>>(part, part2, st9, 9, 0, 1024, 1024);
  conv_small6_kernel<9,8,false><<<1024, 256, 0, stream>>>(
      a1, 8, plddt, 1, st9, conv_p_w, conv_p_b, alpha,
      (const float*)nullptr, part, part2, 128);
  statsB_kernel<<<8, 256, 0, stream>>>(part + (size_t)128*1024,
                                       part2 + (size_t)128*1024,
                                       st136, 136, 128, 1024, 1024);
  agg_ln1_kernel<<<256, 512, 0, stream>>>(alpha, z, v, ln1_g, ln1_b, h1b);
  prep_kernel<<<730, 256, 0, stream>>>(lin1_w, w1b, conv_z_w, wzb2);
  gemm1_kernel<<<32, 256, 0, stream>>>(h1b, w1b, lin1_b, y);
  outB2_kernel<<<128, 256, 0, stream>>>(y, x, ln2_g, ln2_b, lin2_w, lin2_b,
                                        lnf_g, lnf_b, xout);
  conv_z7_kernel<<<1024, 256, 0, stream>>>(z, alpha, st136, wzb2, conv_z_b, zout);
}